// Round 6
// baseline (1081.104 us; speedup 1.0000x reference)
//
#include <hip/hip_runtime.h>
#include <hip/hip_bf16.h>

typedef __attribute__((ext_vector_type(8))) short short8;
typedef __attribute__((ext_vector_type(4))) float floatx4;
typedef __hip_bfloat16 bf16_t;

#define DD 768

__device__ __forceinline__ float sigmoid_f(float x) { return 1.f / (1.f + __expf(-x)); }

__device__ __forceinline__ void gl2lds16(const void* g, void* l) {
  __builtin_amdgcn_global_load_lds((const __attribute__((address_space(1))) void*)g,
                                   (__attribute__((address_space(3))) void*)l, 16, 0, 0);
}

// ---------------------------------------------------------------------------
// 256x256-tile, BK=64, 512-thread (8 waves = 2M x 4N) bf16 MFMA GEMM.
// K split into nPiece uniform pieces of Kpiece; piece ks: koff=ks*Kpiece,
// shift = koff<768 ? shiftL : shiftR, A-column offset csrcA = koff % 768
// (R5 bug: csrcA was dropped -> pieces 1/3 read wrong A columns).
// 4-phase K-loop, minimal LDS reads (24 b128/wave/K-tile):
//   p0: read av0,bv0  stage A-h0'  MFMA (0,0)   wait vmcnt(4)
//   p1: read bv1      stage B-h0'  MFMA (0,1)   wait vmcnt(4)
//   p2: read av1      stage B-h1'  MFMA (1,0)   wait vmcnt(4)
//   p3: (no reads)    stage A-h1'  MFMA (1,1)   no wait, no barrier
// Prologue/stage issue order = consumption order: A0,B0,B1,A1.
// Last tile drains {4,2,0,-} (R3 lesson: the queue stops advancing).
// ---------------------------------------------------------------------------
__global__ __launch_bounds__(512, 2) void gemm256(
    const bf16_t* __restrict__ A, int lda, int M,
    const bf16_t* __restrict__ Wt, int wld, int Kpiece,
    int nRowT, int nColT, int nPiece,
    int shiftL, int shiftR,
    const float* __restrict__ bias0,
    float* __restrict__ out0, float* __restrict__ out1,
    float* __restrict__ out2, float* __restrict__ out3, int N)
{
  __shared__ __attribute__((aligned(16))) unsigned char lds[131072];
  // A: [buf][256][64] bf16 at 0 + buf*32768 ; B: same at 65536 + buf*32768
  const int tid = threadIdx.x;
  const int wave = tid >> 6, lane = tid & 63;
  const int l15 = lane & 15, kq = lane >> 4;
  const int wm = wave >> 2, wn = wave & 3;

  // bijective XCD swizzle (m204)
  const int nwg = gridDim.x;
  const int q8 = nwg >> 3, r8 = nwg & 7;
  const int xcd = blockIdx.x & 7, lin = blockIdx.x >> 3;
  const int wgid = (xcd < r8 ? xcd * (q8 + 1) : r8 * (q8 + 1) + (xcd - r8) * q8) + lin;
  const int per = nRowT * nColT;
  const int ks = wgid / per;
  const int w2 = wgid - ks * per;
  const int rowt = w2 % nRowT, colt = w2 / nRowT;
  const int koff = ks * Kpiece;
  const int shift = (koff < 768) ? shiftL : shiftR;
  const int csrcA = koff - ((koff >= 768) ? 768 : 0);   // A-chunk column offset
  float* out = (ks == 0) ? out0 : ((ks == 1) ? out1 : ((ks == 2) ? out2 : out3));
  const int rowbase = rowt * 256, colbase = colt * 256;

  floatx4 acc[8][4] = {};
  const int nkt = Kpiece >> 6;

  auto stageA = [&](int mh, int kt, int buf) {
    const int kbase = kt << 6;
    #pragma unroll
    for (int rr = 0; rr < 2; ++rr) {
      const int L = rr * 64 + wave * 8;                       // wave-uniform
      const int lrow_base = (L >> 6) * 128 + mh * 64 + (L & 63);
      const int lrow = lrow_base + (lane >> 3);
      const int slotp = (lane & 7) ^ (lrow & 7);
      const int gr = min(rowbase + lrow, M - 1) + shift;
      gl2lds16(A + (size_t)gr * lda + csrcA + kbase + slotp * 8,
               lds + buf * 32768 + lrow_base * 128);
    }
  };
  auto stageB = [&](int nh, int kt, int buf) {
    const int kbase = kt << 6;
    #pragma unroll
    for (int rr = 0; rr < 2; ++rr) {
      const int L = rr * 64 + wave * 8;
      const int lrow_base = (L >> 5) * 64 + nh * 32 + (L & 31);
      const int lrow = lrow_base + (lane >> 3);
      const int slotp = (lane & 7) ^ (lrow & 7);
      const int gn = colbase + lrow;
      gl2lds16(Wt + (size_t)gn * wld + koff + kbase + slotp * 8,
               lds + 65536 + buf * 32768 + lrow_base * 128);
    }
  };

#define READ_A(av_, mh_) \
  _Pragma("unroll") for (int i = 0; i < 4; ++i) { \
    const int r_ = wm * 128 + (mh_) * 64 + i * 16 + l15; \
    _Pragma("unroll") for (int s = 0; s < 2; ++s) { \
      const int sl_ = (s * 4 + kq) ^ (r_ & 7); \
      av_[i][s] = *reinterpret_cast<const short8*>(Ab + r_ * 128 + sl_ * 16); } }

#define READ_B(bv_, nh_) \
  _Pragma("unroll") for (int j = 0; j < 2; ++j) { \
    const int r_ = wn * 64 + (nh_) * 32 + j * 16 + l15; \
    _Pragma("unroll") for (int s = 0; s < 2; ++s) { \
      const int sl_ = (s * 4 + kq) ^ (r_ & 7); \
      bv_[j][s] = *reinterpret_cast<const short8*>(Bb + r_ * 128 + sl_ * 16); } }

#define MFMA_Q(av_, bv_, mb_, nb_) \
  __builtin_amdgcn_s_setprio(1); \
  _Pragma("unroll") for (int i = 0; i < 4; ++i) \
    _Pragma("unroll") for (int j = 0; j < 2; ++j) \
      _Pragma("unroll") for (int s = 0; s < 2; ++s) \
        acc[(mb_) + i][(nb_) + j] = __builtin_amdgcn_mfma_f32_16x16x32_bf16( \
            av_[i][s], bv_[j][s], acc[(mb_) + i][(nb_) + j], 0, 0, 0); \
  __builtin_amdgcn_s_setprio(0);

  // prologue: stage tile 0 into buf 0, consumption order A0,B0,B1,A1
  stageA(0, 0, 0); stageB(0, 0, 0); stageB(1, 0, 0); stageA(1, 0, 0);

  short8 av0[4][2], av1[4][2], bv0[2][2], bv1[2][2];
  int cur = 0;
  for (int t = 0; t < nkt; ++t) {
    const bool notlast = (t + 1 < nkt);
    const unsigned char* Ab = lds + cur * 32768;
    const unsigned char* Bb = lds + 65536 + cur * 32768;

    // phase 0: needs A-h0(t), B-h0(t)
    asm volatile("s_waitcnt vmcnt(4)" ::: "memory");
    __builtin_amdgcn_s_barrier();
    READ_A(av0, 0)
    READ_B(bv0, 0)
    if (notlast) stageA(0, t + 1, cur ^ 1);
    MFMA_Q(av0, bv0, 0, 0)

    // phase 1: needs B-h1(t)
    if (notlast) { asm volatile("s_waitcnt vmcnt(4)" ::: "memory"); }
    else         { asm volatile("s_waitcnt vmcnt(2)" ::: "memory"); }
    __builtin_amdgcn_s_barrier();
    READ_B(bv1, 1)
    if (notlast) stageB(0, t + 1, cur ^ 1);
    MFMA_Q(av0, bv1, 0, 2)

    // phase 2: needs A-h1(t)
    if (notlast) { asm volatile("s_waitcnt vmcnt(4)" ::: "memory"); }
    else         { asm volatile("s_waitcnt vmcnt(0)" ::: "memory"); }
    __builtin_amdgcn_s_barrier();
    READ_A(av1, 1)
    if (notlast) stageB(1, t + 1, cur ^ 1);
    MFMA_Q(av1, bv0, 4, 0)

    // phase 3: register-only
    if (notlast) stageA(1, t + 1, cur ^ 1);
    MFMA_Q(av1, bv1, 4, 2)

    cur ^= 1;
  }
#undef READ_A
#undef READ_B
#undef MFMA_Q

  // epilogue: C/D layout col=lane&15, row=(lane>>4)*4+reg
  const int hi = lane >> 4;
  #pragma unroll
  for (int i = 0; i < 8; ++i)
    #pragma unroll
    for (int j = 0; j < 4; ++j) {
      const int c = colbase + wn * 64 + j * 16 + l15;
      const float bb = bias0 ? bias0[c] : 0.f;
      #pragma unroll
      for (int rg = 0; rg < 4; ++rg) {
        const int r = rowbase + wm * 128 + i * 16 + hi * 4 + rg;
        if (r < M) out[(size_t)r * N + c] = acc[i][j][rg] + bb;
      }
    }
}

// ---------------------------------------------------------------------------
// 128x128 2-phase GEMM (conv + gate: N=768, small grids, per-768-chunk shifts)
// ---------------------------------------------------------------------------
__global__ __launch_bounds__(256) void gemm_shift(
    const bf16_t* __restrict__ A, int lda, int M, int nRowT,
    int s0, int s1, int s2,
    const bf16_t* __restrict__ Wt, int Kdim,
    const float* __restrict__ bias,
    float* __restrict__ out, int N,
    bf16_t* __restrict__ out_bf,
    const float* __restrict__ gate_other)
{
  __shared__ __attribute__((aligned(16))) unsigned char lds[16384];
  const int tid  = threadIdx.x;
  const int wave = tid >> 6, lane = tid & 63;

  const int nwg = gridDim.x;
  const int q8 = nwg >> 3, r8 = nwg & 7;
  const int xcd = blockIdx.x & 7, lin = blockIdx.x >> 3;
  const int wgid = (xcd < r8 ? xcd * (q8 + 1) : r8 * (q8 + 1) + (xcd - r8) * q8) + lin;
  const int rowt = wgid % nRowT, colt = wgid / nRowT;

  const int rowbase = rowt * 128, colbase = colt * 128;
  const int wr = (wave >> 1) * 64, wc = (wave & 1) * 64;

  floatx4 acc[4][4] = {};
  const int nkt = Kdim >> 5;
  const int srow_t = tid >> 2;
  const int sslot  = tid & 3;

  for (int kt = 0; kt < nkt; ++kt) {
    const int kbase = kt << 5;
    const int chunk = kbase / 768;
    const int shift = (chunk == 0) ? s0 : ((chunk == 1) ? s1 : s2);
    const int csrc  = kbase - chunk * 768;

    __syncthreads();
    #pragma unroll
    for (int p = 0; p < 2; ++p) {
      const int row = p * 64 + srow_t;
      const int k8  = sslot ^ ((row >> 1) & 3);
      {
        const int gr = min(rowbase + row, M - 1) + shift;
        gl2lds16(A + (size_t)gr * lda + csrc + k8 * 8, lds + p * 4096 + wave * 1024);
      }
      {
        const int gn = colbase + row;
        gl2lds16(Wt + (size_t)gn * Kdim + kbase + k8 * 8, lds + 8192 + p * 4096 + wave * 1024);
      }
    }
    __syncthreads();

    const int l15 = lane & 15, kq = lane >> 4;
    short8 af[4], bfr[4];
    #pragma unroll
    for (int i = 0; i < 4; ++i) {
      const int arow = wr + i * 16 + l15;
      const int as   = kq ^ ((arow >> 1) & 3);
      af[i] = *reinterpret_cast<const short8*>(&lds[arow * 64 + as * 16]);
      const int brow = wc + i * 16 + l15;
      const int bs   = kq ^ ((brow >> 1) & 3);
      bfr[i] = *reinterpret_cast<const short8*>(&lds[8192 + brow * 64 + bs * 16]);
    }
    #pragma unroll
    for (int i = 0; i < 4; ++i)
      #pragma unroll
      for (int j = 0; j < 4; ++j)
        acc[i][j] = __builtin_amdgcn_mfma_f32_16x16x32_bf16(af[i], bfr[j], acc[i][j], 0, 0, 0);
  }

  const int l15 = lane & 15, hi = lane >> 4;
  #pragma unroll
  for (int i = 0; i < 4; ++i)
    #pragma unroll
    for (int j = 0; j < 4; ++j)
      #pragma unroll
      for (int rg = 0; rg < 4; ++rg) {
        const int r = rowbase + wr + i * 16 + hi * 4 + rg;
        const int c = colbase + wc + j * 16 + l15;
        if (r < M) {
          float v = acc[i][j][rg] + bias[c];
          if (gate_other) v = gate_other[(size_t)r * N + c] * sigmoid_f(v);
          out[(size_t)r * N + c] = v;
          if (out_bf) out_bf[(size_t)r * N + c] = __float2bfloat16(v);
        }
      }
}

__global__ void transpose_cvt(const float* __restrict__ in, bf16_t* __restrict__ out,
                              int in_ld, int out_ld)
{
  __shared__ float tile[32][33];
  const int n0 = blockIdx.x * 32, k0 = blockIdx.y * 32;
  const int tx = threadIdx.x, ty = threadIdx.y;
  #pragma unroll
  for (int yy = ty; yy < 32; yy += 8)
    tile[yy][tx] = in[(size_t)(k0 + yy) * in_ld + n0 + tx];
  __syncthreads();
  #pragma unroll
  for (int yy = ty; yy < 32; yy += 8)
    out[(size_t)(n0 + yy) * out_ld + k0 + tx] = __float2bfloat16(tile[tx][yy]);
}

__global__ void build_wct(const float* __restrict__ cw, bf16_t* __restrict__ wct) {
  const int idx = blockIdx.x * 256 + threadIdx.x;
  const int o = idx / 2304, c = idx - o * 2304;
  const int k = c / 768, i = c - k * 768;
  wct[idx] = __float2bfloat16(cw[o * 2304 + i * 3 + k]);
}

__global__ void build_bias(const float* __restrict__ bmv, const float* __restrict__ bmg,
                           const float* __restrict__ brg, const float* __restrict__ bhw,
                           float* __restrict__ out) {
  const int i = blockIdx.x * 256 + threadIdx.x;
  float v;
  if (i < 768) v = bmv[i];
  else if (i < 1536) v = bmg[i - 768];
  else if (i < 2304) v = brg[i - 1536];
  else v = bhw[i - 2304];
  out[i] = v;
}

__global__ void embed_k(const int* __restrict__ x, const float* __restrict__ emb,
                        const float* __restrict__ pos, bf16_t* __restrict__ hpad) {
  const int t = blockIdx.x, tid = threadIdx.x;
  int id = 0, tt = t - 2;
  if (t >= 2) id = x[tt];
  #pragma unroll
  for (int q = 0; q < 3; ++q) {
    const int d = tid + q * 256;
    float v = 0.f;
    if (t >= 2) v = emb[(size_t)id * DD + d] + pos[(size_t)tt * DD + d];
    hpad[(size_t)t * DD + d] = __float2bfloat16(v);
  }
}

// one block per output row t. 4 K-piece partials summed here; bias added here.
__global__ __launch_bounds__(256) void merge_ew(
    const bf16_t* __restrict__ curOldB, const float* __restrict__ curOldF,
    bf16_t* __restrict__ curNewB, float* __restrict__ curNewF,
    const float* __restrict__ t0, const float* __restrict__ t1,
    const float* __restrict__ t2, const float* __restrict__ t3,
    const float* __restrict__ bias_big,
    const float* __restrict__ rmsw, int step)
{
  const int t = blockIdx.x, tid = threadIdx.x;
  if (t < step) {
    const uint4* sF = (const uint4*)(curOldF + (size_t)t * DD);
    uint4* dF = (uint4*)(curNewF + (size_t)t * DD);
    if (tid < 192) dF[tid] = sF[tid];
    const uint4* sB = (const uint4*)(curOldB + (size_t)t * DD);
    uint4* dB = (uint4*)(curNewB + (size_t)t * DD);
    if (tid < 96) dB[tid] = sB[tid];
    return;
  }
  const int r = t - step;
  const size_t rb = (size_t)r * 3072;
  auto col = [&](int c) {
    return t0[rb + c] + t1[rb + c] + t2[rb + c] + t3[rb + c] + bias_big[c];
  };
  float mv[3]; float ss = 0.f;
  #pragma unroll
  for (int q = 0; q < 3; ++q) {
    const int d = tid + q * 256;
    const float m = col(d) * sigmoid_f(col(768 + d));
    mv[q] = m; ss += m * m;
  }
  #pragma unroll
  for (int o = 32; o >= 1; o >>= 1) ss += __shfl_down(ss, o, 64);
  __shared__ float red[4];
  if ((tid & 63) == 0) red[tid >> 6] = ss;
  __syncthreads();
  const float tot = red[0] + red[1] + red[2] + red[3];
  const float scale = rsqrtf(tot * (1.f / 768.f) + 1.1920929e-07f);
  #pragma unroll
  for (int q = 0; q < 3; ++q) {
    const int d = tid + q * 256;
    float merged = mv[q] * scale * rmsw[d];
    const float right = curOldF[(size_t)t * DD + d];
    const float left  = curOldF[(size_t)r * DD + d];
    const float hg = sigmoid_f(col(2304 + d));
    merged = hg * merged + (1.f - hg) * right;
    const float rg = sigmoid_f(col(1536 + d));
    merged = rg * merged + (1.f - rg) * (left + right) * 0.5f;
    curNewF[(size_t)t * DD + d] = merged;
    curNewB[(size_t)t * DD + d] = __float2bfloat16(merged);
  }
}

extern "C" void kernel_launch(void* const* d_in, const int* in_sizes, int n_in,
                              void* d_out, int out_size, void* d_ws, size_t ws_size,
                              hipStream_t stream) {
  const int*   x      = (const int*)  d_in[0];
  const float* emb    = (const float*)d_in[1];
  const float* pos    = (const float*)d_in[2];
  const float* conv_w = (const float*)d_in[3];
  const float* conv_b = (const float*)d_in[4];
  const float* wg1    = (const float*)d_in[5];
  const float* bg1    = (const float*)d_in[6];
  const float* wmv    = (const float*)d_in[7];
  const float* bmv    = (const float*)d_in[8];
  const float* wmg    = (const float*)d_in[9];
  const float* bmg    = (const float*)d_in[10];
  const float* wrg    = (const float*)d_in[11];
  const float* brg    = (const float*)d_in[12];
  const float* whw    = (const float*)d_in[13];
  const float* bhw    = (const float*)d_in[14];
  const float* rmsw   = (const float*)d_in[15];
  const float* wpred  = (const float*)d_in[16];
  const float* bpred  = (const float*)d_in[17];

  char* ws = (char*)d_ws;
  size_t off = 0;
  auto carve = [&](size_t bytes) { char* p = ws + off; off += (bytes + 255) & ~(size_t)255; return p; };
  bf16_t* wpred_t  = (bf16_t*)carve(32000ull * 768 * 2);
  bf16_t* Wbig_t   = (bf16_t*)carve(3072ull * 1536 * 2);
  bf16_t* wc_t     = (bf16_t*)carve(768ull * 2304 * 2);
  bf16_t* wg1_t    = (bf16_t*)carve(768ull * 768 * 2);
  float*  bias_big = (float*) carve(3072 * 4);
  bf16_t* h_pad    = (bf16_t*)carve(2050ull * 768 * 2);
  float*  hconv    = (float*) carve(2048ull * 768 * 4);
  bf16_t* hconv_bf = (bf16_t*)carve(2048ull * 768 * 2);
  bf16_t* currA_b  = (bf16_t*)carve(2048ull * 768 * 2);
  bf16_t* currB_b  = (bf16_t*)carve(2048ull * 768 * 2);
  float*  currA_f  = (float*) carve(2048ull * 768 * 4);
  float*  currB_f  = (float*) carve(2048ull * 768 * 4);
  float*  tmp      = (float*) carve(2048ull * 3072 * 4);
  // 3 more K-piece partial buffers live in d_out (262 MB, dead until final GEMM)
  float*  tmp2     = (float*)d_out;
  float*  tmp3     = tmp2 + 2048ull * 3072;
  float*  tmp4     = tmp3 + 2048ull * 3072;

  const dim3 tb(32, 8);
  hipMemsetAsync(Wbig_t + 2304ull * 1536, 0, 768ull * 1536 * 2, stream);
  transpose_cvt<<<dim3(24, 48), tb, 0, stream>>>(wmv, Wbig_t,                        768, 1536);
  transpose_cvt<<<dim3(24, 48), tb, 0, stream>>>(wmg, Wbig_t + 768ull * 1536,        768, 1536);
  transpose_cvt<<<dim3(24, 48), tb, 0, stream>>>(wrg, Wbig_t + 1536ull * 1536,       768, 1536);
  transpose_cvt<<<dim3(24, 24), tb, 0, stream>>>(whw, Wbig_t + 2304ull * 1536 + 768, 768, 1536);
  transpose_cvt<<<dim3(24, 24), tb, 0, stream>>>(wg1, wg1_t, 768, 768);
  transpose_cvt<<<dim3(1000, 24), tb, 0, stream>>>(wpred, wpred_t, 32000, 768);
  build_wct<<<6912, 256, 0, stream>>>(conv_w, wc_t);
  build_bias<<<12, 256, 0, stream>>>(bmv, bmg, brg, bhw, bias_big);

  embed_k<<<2050, 256, 0, stream>>>(x, emb, pos, h_pad);

  // causal conv as shifted GEMM (3 chunks of h_pad rows t+0,t+1,t+2)
  gemm_shift<<<96, 256, 0, stream>>>(h_pad, 768, 2048, 16, 0, 1, 2,
                                     wc_t, 2304, conv_b, hconv, 768, hconv_bf, nullptr);
  // curr0 = hconv * sigmoid(hconv @ wg1 + bg1)
  gemm_shift<<<96, 256, 0, stream>>>(hconv_bf, 768, 2048, 16, 0, 0, 0,
                                     wg1_t, 768, bg1, currA_f, 768, currA_b, hconv);

  bf16_t* curB = currA_b; float* curF = currA_f;
  bf16_t* nxtB = currB_b; float* nxtF = currB_f;
  for (int step = 1; step < 2048; step <<= 1) {
    const int M = 2048 - step;
    const int nRowT = (M + 255) / 256;
    // 4-way K-split (Kpiece=384): pieces 0,1 = left (shift 0), 2,3 = right (shift step)
    gemm256<<<4 * nRowT * 12, 512, 0, stream>>>(
        curB, 768, M, Wbig_t, 1536, 384, nRowT, 12, 4,
        0, step, nullptr, tmp, tmp2, tmp3, tmp4, 3072);
    merge_ew<<<2048, 256, 0, stream>>>(curB, curF, nxtB, nxtF,
                                       tmp, tmp2, tmp3, tmp4, bias_big, rmsw, step);
    { bf16_t* tb_ = curB; curB = nxtB; nxtB = tb_; }
    { float*  tf_ = curF; curF = nxtF; nxtF = tf_; }
  }

  // logits = curr @ wpred + bpred
  gemm256<<<8 * 125, 512, 0, stream>>>(curB, 768, 2048, wpred_t, 768, 768, 8, 125, 1,
                                       0, 0, bpred, (float*)d_out, nullptr, nullptr, nullptr, 32000);
}

// Round 7
// 868.049 us; speedup vs baseline: 1.2454x; 1.2454x over previous
//
#include <hip/hip_runtime.h>
#include <hip/hip_bf16.h>

typedef __attribute__((ext_vector_type(8))) short short8;
typedef __attribute__((ext_vector_type(4))) float floatx4;
typedef __hip_bfloat16 bf16_t;

#define DD 768

__device__ __forceinline__ float sigmoid_f(float x) { return 1.f / (1.f + __expf(-x)); }

__device__ __forceinline__ void gl2lds16(const void* g, void* l) {
  __builtin_amdgcn_global_load_lds((const __attribute__((address_space(1))) void*)g,
                                   (__attribute__((address_space(3))) void*)l, 16, 0, 0);
}

// ---------------------------------------------------------------------------
// 256x256-tile, BK=64, 512-thread (8 waves = 2M x 4N) bf16 MFMA GEMM.
// K split into nPiece pieces of Kpiece; piece ks: koff=ks*Kpiece,
// shift = (koff/768)*shiftStride, A-column offset csrcA = koff % 768.
// 4-phase K-loop, minimal LDS reads (24 b128/wave/K-tile):
//   p0: read av0,bv0  stage A-h0'  MFMA (0,0)   wait vmcnt(4)
//   p1: read bv1      stage B-h0'  MFMA (0,1)   wait vmcnt(4)
//   p2: read av1      stage B-h1'  MFMA (1,0)   wait vmcnt(4)
//   p3: (no reads)    stage A-h1'  MFMA (1,1)   no wait, no barrier
// Prologue/stage issue order = consumption order: A0,B0,B1,A1.
// Last tile drains {4,2,0,-} (R3 lesson: the queue stops advancing).
// ---------------------------------------------------------------------------
__global__ __launch_bounds__(512, 2) void gemm256(
    const bf16_t* __restrict__ A, int lda, int M,
    const bf16_t* __restrict__ Wt, int wld, int Kpiece,
    int nRowT, int nColT, int nPiece,
    int shiftStride,
    const float* __restrict__ bias0,
    float* __restrict__ out0, float* __restrict__ out1,
    float* __restrict__ out2, float* __restrict__ out3, int N)
{
  __shared__ __attribute__((aligned(16))) unsigned char lds[131072];
  // A: [buf][256][64] bf16 at 0 + buf*32768 ; B: same at 65536 + buf*32768
  const int tid = threadIdx.x;
  const int wave = tid >> 6, lane = tid & 63;
  const int l15 = lane & 15, kq = lane >> 4;
  const int wm = wave >> 2, wn = wave & 3;

  // bijective XCD swizzle (m204)
  const int nwg = gridDim.x;
  const int q8 = nwg >> 3, r8 = nwg & 7;
  const int xcd = blockIdx.x & 7, lin = blockIdx.x >> 3;
  const int wgid = (xcd < r8 ? xcd * (q8 + 1) : r8 * (q8 + 1) + (xcd - r8) * q8) + lin;
  const int per = nRowT * nColT;
  const int ks = wgid / per;
  const int w2 = wgid - ks * per;
  const int rowt = w2 % nRowT, colt = w2 / nRowT;
  const int koff = ks * Kpiece;
  const int chunk = koff / 768;
  const int shift = chunk * shiftStride;
  const int csrcA = koff - chunk * 768;                 // A-chunk column offset
  float* out = (ks == 0) ? out0 : ((ks == 1) ? out1 : ((ks == 2) ? out2 : out3));
  const int rowbase = rowt * 256, colbase = colt * 256;

  floatx4 acc[8][4] = {};
  const int nkt = Kpiece >> 6;

  auto stageA = [&](int mh, int kt, int buf) {
    const int kbase = kt << 6;
    #pragma unroll
    for (int rr = 0; rr < 2; ++rr) {
      const int L = rr * 64 + wave * 8;                       // wave-uniform
      const int lrow_base = (L >> 6) * 128 + mh * 64 + (L & 63);
      const int lrow = lrow_base + (lane >> 3);
      const int slotp = (lane & 7) ^ (lrow & 7);
      const int gr = min(rowbase + lrow, M - 1) + shift;
      gl2lds16(A + (size_t)gr * lda + csrcA + kbase + slotp * 8,
               lds + buf * 32768 + lrow_base * 128);
    }
  };
  auto stageB = [&](int nh, int kt, int buf) {
    const int kbase = kt << 6;
    #pragma unroll
    for (int rr = 0; rr < 2; ++rr) {
      const int L = rr * 64 + wave * 8;
      const int lrow_base = (L >> 5) * 64 + nh * 32 + (L & 31);
      const int lrow = lrow_base + (lane >> 3);
      const int slotp = (lane & 7) ^ (lrow & 7);
      const int gn = colbase + lrow;
      gl2lds16(Wt + (size_t)gn * wld + koff + kbase + slotp * 8,
               lds + 65536 + buf * 32768 + lrow_base * 128);
    }
  };

#define READ_A(av_, mh_) \
  _Pragma("unroll") for (int i = 0; i < 4; ++i) { \
    const int r_ = wm * 128 + (mh_) * 64 + i * 16 + l15; \
    _Pragma("unroll") for (int s = 0; s < 2; ++s) { \
      const int sl_ = (s * 4 + kq) ^ (r_ & 7); \
      av_[i][s] = *reinterpret_cast<const short8*>(Ab + r_ * 128 + sl_ * 16); } }

#define READ_B(bv_, nh_) \
  _Pragma("unroll") for (int j = 0; j < 2; ++j) { \
    const int r_ = wn * 64 + (nh_) * 32 + j * 16 + l15; \
    _Pragma("unroll") for (int s = 0; s < 2; ++s) { \
      const int sl_ = (s * 4 + kq) ^ (r_ & 7); \
      bv_[j][s] = *reinterpret_cast<const short8*>(Bb + r_ * 128 + sl_ * 16); } }

#define MFMA_Q(av_, bv_, mb_, nb_) \
  __builtin_amdgcn_s_setprio(1); \
  _Pragma("unroll") for (int i = 0; i < 4; ++i) \
    _Pragma("unroll") for (int j = 0; j < 2; ++j) \
      _Pragma("unroll") for (int s = 0; s < 2; ++s) \
        acc[(mb_) + i][(nb_) + j] = __builtin_amdgcn_mfma_f32_16x16x32_bf16( \
            av_[i][s], bv_[j][s], acc[(mb_) + i][(nb_) + j], 0, 0, 0); \
  __builtin_amdgcn_s_setprio(0);

  // prologue: stage tile 0 into buf 0, consumption order A0,B0,B1,A1
  stageA(0, 0, 0); stageB(0, 0, 0); stageB(1, 0, 0); stageA(1, 0, 0);

  short8 av0[4][2], av1[4][2], bv0[2][2], bv1[2][2];
  int cur = 0;
  for (int t = 0; t < nkt; ++t) {
    const bool notlast = (t + 1 < nkt);
    const unsigned char* Ab = lds + cur * 32768;
    const unsigned char* Bb = lds + 65536 + cur * 32768;

    // phase 0: needs A-h0(t), B-h0(t)
    asm volatile("s_waitcnt vmcnt(4)" ::: "memory");
    __builtin_amdgcn_s_barrier();
    READ_A(av0, 0)
    READ_B(bv0, 0)
    if (notlast) stageA(0, t + 1, cur ^ 1);
    MFMA_Q(av0, bv0, 0, 0)

    // phase 1: needs B-h1(t)
    if (notlast) { asm volatile("s_waitcnt vmcnt(4)" ::: "memory"); }
    else         { asm volatile("s_waitcnt vmcnt(2)" ::: "memory"); }
    __builtin_amdgcn_s_barrier();
    READ_B(bv1, 1)
    if (notlast) stageB(0, t + 1, cur ^ 1);
    MFMA_Q(av0, bv1, 0, 2)

    // phase 2: needs A-h1(t)
    if (notlast) { asm volatile("s_waitcnt vmcnt(4)" ::: "memory"); }
    else         { asm volatile("s_waitcnt vmcnt(0)" ::: "memory"); }
    __builtin_amdgcn_s_barrier();
    READ_A(av1, 1)
    if (notlast) stageB(1, t + 1, cur ^ 1);
    MFMA_Q(av1, bv0, 4, 0)

    // phase 3: register-only
    if (notlast) stageA(1, t + 1, cur ^ 1);
    MFMA_Q(av1, bv1, 4, 2)

    cur ^= 1;
  }
#undef READ_A
#undef READ_B
#undef MFMA_Q

  // epilogue: C/D layout col=lane&15, row=(lane>>4)*4+reg
  const int hi = lane >> 4;
  #pragma unroll
  for (int i = 0; i < 8; ++i)
    #pragma unroll
    for (int j = 0; j < 4; ++j) {
      const int c = colbase + wn * 64 + j * 16 + l15;
      const float bb = bias0 ? bias0[c] : 0.f;
      #pragma unroll
      for (int rg = 0; rg < 4; ++rg) {
        const int r = rowbase + wm * 128 + i * 16 + hi * 4 + rg;
        if (r < M) out[(size_t)r * N + c] = acc[i][j][rg] + bb;
      }
    }
}

// ---------------------------------------------------------------------------
// 128x128 2-phase GEMM (conv + gate: N=768, small grids, per-768-chunk shifts)
// ---------------------------------------------------------------------------
__global__ __launch_bounds__(256) void gemm_shift(
    const bf16_t* __restrict__ A, int lda, int M, int nRowT,
    int s0, int s1, int s2,
    const bf16_t* __restrict__ Wt, int Kdim,
    const float* __restrict__ bias,
    float* __restrict__ out, int N,
    bf16_t* __restrict__ out_bf,
    const float* __restrict__ gate_other)
{
  __shared__ __attribute__((aligned(16))) unsigned char lds[16384];
  const int tid  = threadIdx.x;
  const int wave = tid >> 6, lane = tid & 63;

  const int nwg = gridDim.x;
  const int q8 = nwg >> 3, r8 = nwg & 7;
  const int xcd = blockIdx.x & 7, lin = blockIdx.x >> 3;
  const int wgid = (xcd < r8 ? xcd * (q8 + 1) : r8 * (q8 + 1) + (xcd - r8) * q8) + lin;
  const int rowt = wgid % nRowT, colt = wgid / nRowT;

  const int rowbase = rowt * 128, colbase = colt * 128;
  const int wr = (wave >> 1) * 64, wc = (wave & 1) * 64;

  floatx4 acc[4][4] = {};
  const int nkt = Kdim >> 5;
  const int srow_t = tid >> 2;
  const int sslot  = tid & 3;

  for (int kt = 0; kt < nkt; ++kt) {
    const int kbase = kt << 5;
    const int chunk = kbase / 768;
    const int shift = (chunk == 0) ? s0 : ((chunk == 1) ? s1 : s2);
    const int csrc  = kbase - chunk * 768;

    __syncthreads();
    #pragma unroll
    for (int p = 0; p < 2; ++p) {
      const int row = p * 64 + srow_t;
      const int k8  = sslot ^ ((row >> 1) & 3);
      {
        const int gr = min(rowbase + row, M - 1) + shift;
        gl2lds16(A + (size_t)gr * lda + csrc + k8 * 8, lds + p * 4096 + wave * 1024);
      }
      {
        const int gn = colbase + row;
        gl2lds16(Wt + (size_t)gn * Kdim + kbase + k8 * 8, lds + 8192 + p * 4096 + wave * 1024);
      }
    }
    __syncthreads();

    const int l15 = lane & 15, kq = lane >> 4;
    short8 af[4], bfr[4];
    #pragma unroll
    for (int i = 0; i < 4; ++i) {
      const int arow = wr + i * 16 + l15;
      const int as   = kq ^ ((arow >> 1) & 3);
      af[i] = *reinterpret_cast<const short8*>(&lds[arow * 64 + as * 16]);
      const int brow = wc + i * 16 + l15;
      const int bs   = kq ^ ((brow >> 1) & 3);
      bfr[i] = *reinterpret_cast<const short8*>(&lds[8192 + brow * 64 + bs * 16]);
    }
    #pragma unroll
    for (int i = 0; i < 4; ++i)
      #pragma unroll
      for (int j = 0; j < 4; ++j)
        acc[i][j] = __builtin_amdgcn_mfma_f32_16x16x32_bf16(af[i], bfr[j], acc[i][j], 0, 0, 0);
  }

  const int l15 = lane & 15, hi = lane >> 4;
  #pragma unroll
  for (int i = 0; i < 4; ++i)
    #pragma unroll
    for (int j = 0; j < 4; ++j)
      #pragma unroll
      for (int rg = 0; rg < 4; ++rg) {
        const int r = rowbase + wr + i * 16 + hi * 4 + rg;
        const int c = colbase + wc + j * 16 + l15;
        if (r < M) {
          float v = acc[i][j][rg] + bias[c];
          if (gate_other) v = gate_other[(size_t)r * N + c] * sigmoid_f(v);
          out[(size_t)r * N + c] = v;
          if (out_bf) out_bf[(size_t)r * N + c] = __float2bfloat16(v);
        }
      }
}

__global__ void transpose_cvt(const float* __restrict__ in, bf16_t* __restrict__ out,
                              int in_ld, int out_ld)
{
  __shared__ float tile[32][33];
  const int n0 = blockIdx.x * 32, k0 = blockIdx.y * 32;
  const int tx = threadIdx.x, ty = threadIdx.y;
  #pragma unroll
  for (int yy = ty; yy < 32; yy += 8)
    tile[yy][tx] = in[(size_t)(k0 + yy) * in_ld + n0 + tx];
  __syncthreads();
  #pragma unroll
  for (int yy = ty; yy < 32; yy += 8)
    out[(size_t)(n0 + yy) * out_ld + k0 + tx] = __float2bfloat16(tile[tx][yy]);
}

__global__ void build_wct(const float* __restrict__ cw, bf16_t* __restrict__ wct) {
  const int idx = blockIdx.x * 256 + threadIdx.x;
  const int o = idx / 2304, c = idx - o * 2304;
  const int k = c / 768, i = c - k * 768;
  wct[idx] = __float2bfloat16(cw[o * 2304 + i * 3 + k]);
}

__global__ void build_bias(const float* __restrict__ bmv, const float* __restrict__ bmg,
                           const float* __restrict__ brg, const float* __restrict__ bhw,
                           float* __restrict__ out) {
  const int i = blockIdx.x * 256 + threadIdx.x;
  float v;
  if (i < 768) v = bmv[i];
  else if (i < 1536) v = bmg[i - 768];
  else if (i < 2304) v = brg[i - 1536];
  else v = bhw[i - 2304];
  out[i] = v;
}

__global__ void embed_k(const int* __restrict__ x, const float* __restrict__ emb,
                        const float* __restrict__ pos, bf16_t* __restrict__ hpad) {
  const int t = blockIdx.x, tid = threadIdx.x;
  int id = 0, tt = t - 2;
  if (t >= 2) id = x[tt];
  #pragma unroll
  for (int q = 0; q < 3; ++q) {
    const int d = tid + q * 256;
    float v = 0.f;
    if (t >= 2) v = emb[(size_t)id * DD + d] + pos[(size_t)tt * DD + d];
    hpad[(size_t)t * DD + d] = __float2bfloat16(v);
  }
}

// one block per output row t. 2 K-piece partials summed here; bias added here.
__global__ __launch_bounds__(256) void merge_ew(
    const bf16_t* __restrict__ curOldB, const float* __restrict__ curOldF,
    bf16_t* __restrict__ curNewB, float* __restrict__ curNewF,
    const float* __restrict__ t0, const float* __restrict__ t1,
    const float* __restrict__ bias_big,
    const float* __restrict__ rmsw, int step)
{
  const int t = blockIdx.x, tid = threadIdx.x;
  if (t < step) {
    const uint4* sF = (const uint4*)(curOldF + (size_t)t * DD);
    uint4* dF = (uint4*)(curNewF + (size_t)t * DD);
    if (tid < 192) dF[tid] = sF[tid];
    const uint4* sB = (const uint4*)(curOldB + (size_t)t * DD);
    uint4* dB = (uint4*)(curNewB + (size_t)t * DD);
    if (tid < 96) dB[tid] = sB[tid];
    return;
  }
  const int r = t - step;
  const size_t rb = (size_t)r * 3072;
  auto col = [&](int c) {
    return t0[rb + c] + t1[rb + c] + bias_big[c];
  };
  float mv[3]; float ss = 0.f;
  #pragma unroll
  for (int q = 0; q < 3; ++q) {
    const int d = tid + q * 256;
    const float m = col(d) * sigmoid_f(col(768 + d));
    mv[q] = m; ss += m * m;
  }
  #pragma unroll
  for (int o = 32; o >= 1; o >>= 1) ss += __shfl_down(ss, o, 64);
  __shared__ float red[4];
  if ((tid & 63) == 0) red[tid >> 6] = ss;
  __syncthreads();
  const float tot = red[0] + red[1] + red[2] + red[3];
  const float scale = rsqrtf(tot * (1.f / 768.f) + 1.1920929e-07f);
  #pragma unroll
  for (int q = 0; q < 3; ++q) {
    const int d = tid + q * 256;
    float merged = mv[q] * scale * rmsw[d];
    const float right = curOldF[(size_t)t * DD + d];
    const float left  = curOldF[(size_t)r * DD + d];
    const float hg = sigmoid_f(col(2304 + d));
    merged = hg * merged + (1.f - hg) * right;
    const float rg = sigmoid_f(col(1536 + d));
    merged = rg * merged + (1.f - rg) * (left + right) * 0.5f;
    curNewF[(size_t)t * DD + d] = merged;
    curNewB[(size_t)t * DD + d] = __float2bfloat16(merged);
  }
}

extern "C" void kernel_launch(void* const* d_in, const int* in_sizes, int n_in,
                              void* d_out, int out_size, void* d_ws, size_t ws_size,
                              hipStream_t stream) {
  const int*   x      = (const int*)  d_in[0];
  const float* emb    = (const float*)d_in[1];
  const float* pos    = (const float*)d_in[2];
  const float* conv_w = (const float*)d_in[3];
  const float* conv_b = (const float*)d_in[4];
  const float* wg1    = (const float*)d_in[5];
  const float* bg1    = (const float*)d_in[6];
  const float* wmv    = (const float*)d_in[7];
  const float* bmv    = (const float*)d_in[8];
  const float* wmg    = (const float*)d_in[9];
  const float* bmg    = (const float*)d_in[10];
  const float* wrg    = (const float*)d_in[11];
  const float* brg    = (const float*)d_in[12];
  const float* whw    = (const float*)d_in[13];
  const float* bhw    = (const float*)d_in[14];
  const float* rmsw   = (const float*)d_in[15];
  const float* wpred  = (const float*)d_in[16];
  const float* bpred  = (const float*)d_in[17];

  char* ws = (char*)d_ws;
  size_t off = 0;
  auto carve = [&](size_t bytes) { char* p = ws + off; off += (bytes + 255) & ~(size_t)255; return p; };
  bf16_t* wpred_t  = (bf16_t*)carve(32000ull * 768 * 2);
  bf16_t* Wbig_t   = (bf16_t*)carve(3072ull * 1536 * 2);
  bf16_t* wc_t     = (bf16_t*)carve(768ull * 2304 * 2);
  bf16_t* wg1_t    = (bf16_t*)carve(768ull * 768 * 2);
  float*  bias_big = (float*) carve(3072 * 4);
  bf16_t* h_pad    = (bf16_t*)carve(2050ull * 768 * 2);
  float*  hconv    = (float*) carve(2048ull * 768 * 4);
  bf16_t* hconv_bf = (bf16_t*)carve(2048ull * 768 * 2);
  bf16_t* currA_b  = (bf16_t*)carve(2048ull * 768 * 2);
  bf16_t* currB_b  = (bf16_t*)carve(2048ull * 768 * 2);
  float*  currA_f  = (float*) carve(2048ull * 768 * 4);
  float*  currB_f  = (float*) carve(2048ull * 768 * 4);
  float*  tmp      = (float*) carve(2048ull * 3072 * 4);
  // second K-piece partial buffer lives in d_out (262 MB, dead until final GEMM)
  float*  tmp2     = (float*)d_out;

  const dim3 tb(32, 8);
  hipMemsetAsync(Wbig_t + 2304ull * 1536, 0, 768ull * 1536 * 2, stream);
  transpose_cvt<<<dim3(24, 48), tb, 0, stream>>>(wmv, Wbig_t,                        768, 1536);
  transpose_cvt<<<dim3(24, 48), tb, 0, stream>>>(wmg, Wbig_t + 768ull * 1536,        768, 1536);
  transpose_cvt<<<dim3(24, 48), tb, 0, stream>>>(wrg, Wbig_t + 1536ull * 1536,       768, 1536);
  transpose_cvt<<<dim3(24, 24), tb, 0, stream>>>(whw, Wbig_t + 2304ull * 1536 + 768, 768, 1536);
  transpose_cvt<<<dim3(24, 24), tb, 0, stream>>>(wg1, wg1_t, 768, 768);
  transpose_cvt<<<dim3(1000, 24), tb, 0, stream>>>(wpred, wpred_t, 32000, 768);
  build_wct<<<6912, 256, 0, stream>>>(conv_w, wc_t);
  build_bias<<<12, 256, 0, stream>>>(bmv, bmg, brg, bhw, bias_big);

  embed_k<<<2050, 256, 0, stream>>>(x, emb, pos, h_pad);

  // causal conv as shifted GEMM (3 chunks of h_pad rows t+0,t+1,t+2)
  gemm_shift<<<96, 256, 0, stream>>>(h_pad, 768, 2048, 16, 0, 1, 2,
                                     wc_t, 2304, conv_b, hconv, 768, hconv_bf, nullptr);
  // curr0 = hconv * sigmoid(hconv @ wg1 + bg1)
  gemm_shift<<<96, 256, 0, stream>>>(hconv_bf, 768, 2048, 16, 0, 0, 0,
                                     wg1_t, 768, bg1, currA_f, 768, currA_b, hconv);

  bf16_t* curB = currA_b; float* curF = currA_f;
  bf16_t* nxtB = currB_b; float* nxtF = currB_f;
  for (int step = 1; step < 2048; step <<= 1) {
    const int M = 2048 - step;
    const int nRowT = (M + 255) / 256;
    // 2-way K-split (Kpiece=768): piece 0 = left (shift 0), piece 1 = right (shift step)
    gemm256<<<2 * nRowT * 12, 512, 0, stream>>>(
        curB, 768, M, Wbig_t, 1536, 768, nRowT, 12, 2,
        step, nullptr, tmp, tmp2, nullptr, nullptr, 3072);
    merge_ew<<<2048, 256, 0, stream>>>(curB, curF, nxtB, nxtF,
                                       tmp, tmp2, bias_big, rmsw, step);
    { bf16_t* tb_ = curB; curB = nxtB; nxtB = tb_; }
    { float*  tf_ = curF; curF = nxtF; nxtF = tf_; }
  }

  // logits = curr @ wpred + bpred
  gemm256<<<8 * 125, 512, 0, stream>>>(curB, 768, 2048, wpred_t, 768, 768, 8, 125, 1,
                                       0, bpred, (float*)d_out, nullptr, nullptr, nullptr, 32000);
}

// Round 8
// 866.078 us; speedup vs baseline: 1.2483x; 1.0023x over previous
//
#include <hip/hip_runtime.h>
#include <hip/hip_bf16.h>

typedef __attribute__((ext_vector_type(8))) short short8;
typedef __attribute__((ext_vector_type(4))) float floatx4;
typedef __hip_bfloat16 bf16_t;

#define DD 768

__device__ __forceinline__ float sigmoid_f(float x) { return 1.f / (1.f + __expf(-x)); }

__device__ __forceinline__ void gl2lds16(const void* g, void* l) {
  __builtin_amdgcn_global_load_lds((const __attribute__((address_space(1))) void*)g,
                                   (__attribute__((address_space(3))) void*)l, 16, 0, 0);
}

// ---------------------------------------------------------------------------
// 256x256-tile, BK=64, 512-thread (8 waves = 2M x 4N) bf16 MFMA GEMM.
// K split into nPiece pieces of Kpiece; piece ks: koff=ks*Kpiece,
// shift = (koff/768)*shiftStride, A-column offset csrcA = koff % 768.
//
// Pipeline (R8): A double-buffered (4-phase lead, L2-resident operand),
// B TRIPLE-buffered (6-phase lead ~1000cyc >= HBM latency — B streams from
// HBM in the final GEMM). LDS = 2*32K + 3*32K = 160 KiB exactly.
// Issue order per tile t: p0:A0(t+1) p1:A1(t+1) p2:B0(t+2) p3:B1(t+2)
// (A issued BEFORE B so waiting for A1 does not retire B(t+1) early).
// Per-wave FIFO ledger (verified steady + prologue + tails, nkt=12/2):
//   p0: wait vmcnt(6)  [last tile: vmcnt(2)] ; barrier; read av0,bv0
//   p1: no wait                              ; read bv1 (retired at p0)
//   p2: wait vmcnt(8)  [last tile: vmcnt(0)] ; barrier; read av1
//   p3: no wait, register-only MFMA
// Stages guarded by t+1<nkt (A) / t+2<nkt (B); prologue issues
// B(0),A(0),B(1) in exactly that queue order.
// ---------------------------------------------------------------------------
__global__ __launch_bounds__(512, 2) void gemm256(
    const bf16_t* __restrict__ A, int lda, int M,
    const bf16_t* __restrict__ Wt, int wld, int Kpiece,
    int nRowT, int nColT, int nPiece,
    int shiftStride,
    const float* __restrict__ bias0,
    float* __restrict__ out0, float* __restrict__ out1,
    float* __restrict__ out2, float* __restrict__ out3, int N)
{
  __shared__ __attribute__((aligned(16))) unsigned char lds[163840];
  // A: [bufA][256][64] bf16 at 0 + bufA*32768 (bufA in {0,1})
  // B: [bufB][256][64] bf16 at 65536 + bufB*32768 (bufB in {0,1,2})
  const int tid = threadIdx.x;
  const int wave = tid >> 6, lane = tid & 63;
  const int l15 = lane & 15, kq = lane >> 4;
  const int wm = wave >> 2, wn = wave & 3;

  // bijective XCD swizzle (m204)
  const int nwg = gridDim.x;
  const int q8 = nwg >> 3, r8 = nwg & 7;
  const int xcd = blockIdx.x & 7, lin = blockIdx.x >> 3;
  const int wgid = (xcd < r8 ? xcd * (q8 + 1) : r8 * (q8 + 1) + (xcd - r8) * q8) + lin;
  const int per = nRowT * nColT;
  const int ks = wgid / per;
  const int w2 = wgid - ks * per;
  const int rowt = w2 % nRowT, colt = w2 / nRowT;
  const int koff = ks * Kpiece;
  const int chunk = koff / 768;
  const int shift = chunk * shiftStride;
  const int csrcA = koff - chunk * 768;                 // A-chunk column offset
  float* out = (ks == 0) ? out0 : ((ks == 1) ? out1 : ((ks == 2) ? out2 : out3));
  const int rowbase = rowt * 256, colbase = colt * 256;

  floatx4 acc[8][4] = {};
  const int nkt = Kpiece >> 6;

  auto stageA = [&](int mh, int kt, int buf) {
    const int kbase = kt << 6;
    #pragma unroll
    for (int rr = 0; rr < 2; ++rr) {
      const int L = rr * 64 + wave * 8;                       // wave-uniform
      const int lrow_base = (L >> 6) * 128 + mh * 64 + (L & 63);
      const int lrow = lrow_base + (lane >> 3);
      const int slotp = (lane & 7) ^ (lrow & 7);
      const int gr = min(rowbase + lrow, M - 1) + shift;
      gl2lds16(A + (size_t)gr * lda + csrcA + kbase + slotp * 8,
               lds + buf * 32768 + lrow_base * 128);
    }
  };
  auto stageB = [&](int nh, int kt, int buf) {
    const int kbase = kt << 6;
    #pragma unroll
    for (int rr = 0; rr < 2; ++rr) {
      const int L = rr * 64 + wave * 8;
      const int lrow_base = (L >> 5) * 64 + nh * 32 + (L & 31);
      const int lrow = lrow_base + (lane >> 3);
      const int slotp = (lane & 7) ^ (lrow & 7);
      const int gn = colbase + lrow;
      gl2lds16(Wt + (size_t)gn * wld + koff + kbase + slotp * 8,
               lds + 65536 + buf * 32768 + lrow_base * 128);
    }
  };

#define READ_A(av_, mh_) \
  _Pragma("unroll") for (int i = 0; i < 4; ++i) { \
    const int r_ = wm * 128 + (mh_) * 64 + i * 16 + l15; \
    _Pragma("unroll") for (int s = 0; s < 2; ++s) { \
      const int sl_ = (s * 4 + kq) ^ (r_ & 7); \
      av_[i][s] = *reinterpret_cast<const short8*>(Ab + r_ * 128 + sl_ * 16); } }

#define READ_B(bv_, nh_) \
  _Pragma("unroll") for (int j = 0; j < 2; ++j) { \
    const int r_ = wn * 64 + (nh_) * 32 + j * 16 + l15; \
    _Pragma("unroll") for (int s = 0; s < 2; ++s) { \
      const int sl_ = (s * 4 + kq) ^ (r_ & 7); \
      bv_[j][s] = *reinterpret_cast<const short8*>(Bb + r_ * 128 + sl_ * 16); } }

#define MFMA_Q(av_, bv_, mb_, nb_) \
  __builtin_amdgcn_s_setprio(1); \
  _Pragma("unroll") for (int i = 0; i < 4; ++i) \
    _Pragma("unroll") for (int j = 0; j < 2; ++j) \
      _Pragma("unroll") for (int s = 0; s < 2; ++s) \
        acc[(mb_) + i][(nb_) + j] = __builtin_amdgcn_mfma_f32_16x16x32_bf16( \
            av_[i][s], bv_[j][s], acc[(mb_) + i][(nb_) + j], 0, 0, 0); \
  __builtin_amdgcn_s_setprio(0);

  // prologue: queue order B0(0),B1(0),A0(0),A1(0),B0(1),B1(1)
  stageB(0, 0, 0); stageB(1, 0, 0);
  stageA(0, 0, 0); stageA(1, 0, 0);
  if (nkt > 1) { stageB(0, 1, 1); stageB(1, 1, 1); }

  short8 av0[4][2], av1[4][2], bv0[2][2], bv1[2][2];
  int curA = 0, curB = 0;
  for (int t = 0; t < nkt; ++t) {
    const bool hasA = (t + 1 < nkt), hasB = (t + 2 < nkt);
    const unsigned char* Ab = lds + curA * 32768;
    const unsigned char* Bb = lds + 65536 + curB * 32768;
    int tgtB = curB + 2; if (tgtB >= 3) tgtB -= 3;

    // p0: consume A0(t), B0(t)
    if (hasA) { asm volatile("s_waitcnt vmcnt(6)" ::: "memory"); }
    else      { asm volatile("s_waitcnt vmcnt(2)" ::: "memory"); }
    __builtin_amdgcn_s_barrier();
    READ_A(av0, 0)
    READ_B(bv0, 0)
    if (hasA) stageA(0, t + 1, curA ^ 1);
    MFMA_Q(av0, bv0, 0, 0)

    // p1: consume B1(t) — already retired by p0's wait (vmcnt(6) covers it)
    READ_B(bv1, 1)
    if (hasA) stageA(1, t + 1, curA ^ 1);
    MFMA_Q(av0, bv1, 0, 2)

    // p2: consume A1(t)
    if (hasA) { asm volatile("s_waitcnt vmcnt(8)" ::: "memory"); }
    else      { asm volatile("s_waitcnt vmcnt(0)" ::: "memory"); }
    __builtin_amdgcn_s_barrier();
    READ_A(av1, 1)
    if (hasB) stageB(0, t + 2, tgtB);
    MFMA_Q(av1, bv0, 4, 0)

    // p3: register-only
    if (hasB) stageB(1, t + 2, tgtB);
    MFMA_Q(av1, bv1, 4, 2)

    curA ^= 1; curB = (curB + 1 == 3) ? 0 : curB + 1;
  }
#undef READ_A
#undef READ_B
#undef MFMA_Q

  // epilogue: C/D layout col=lane&15, row=(lane>>4)*4+reg
  const int hi = lane >> 4;
  #pragma unroll
  for (int i = 0; i < 8; ++i)
    #pragma unroll
    for (int j = 0; j < 4; ++j) {
      const int c = colbase + wn * 64 + j * 16 + l15;
      const float bb = bias0 ? bias0[c] : 0.f;
      #pragma unroll
      for (int rg = 0; rg < 4; ++rg) {
        const int r = rowbase + wm * 128 + i * 16 + hi * 4 + rg;
        if (r < M) out[(size_t)r * N + c] = acc[i][j][rg] + bb;
      }
    }
}

// ---------------------------------------------------------------------------
// 128x128 2-phase GEMM (conv + gate: N=768, small grids, per-768-chunk shifts)
// ---------------------------------------------------------------------------
__global__ __launch_bounds__(256) void gemm_shift(
    const bf16_t* __restrict__ A, int lda, int M, int nRowT,
    int s0, int s1, int s2,
    const bf16_t* __restrict__ Wt, int Kdim,
    const float* __restrict__ bias,
    float* __restrict__ out, int N,
    bf16_t* __restrict__ out_bf,
    const float* __restrict__ gate_other)
{
  __shared__ __attribute__((aligned(16))) unsigned char lds[16384];
  const int tid  = threadIdx.x;
  const int wave = tid >> 6, lane = tid & 63;

  const int nwg = gridDim.x;
  const int q8 = nwg >> 3, r8 = nwg & 7;
  const int xcd = blockIdx.x & 7, lin = blockIdx.x >> 3;
  const int wgid = (xcd < r8 ? xcd * (q8 + 1) : r8 * (q8 + 1) + (xcd - r8) * q8) + lin;
  const int rowt = wgid % nRowT, colt = wgid / nRowT;

  const int rowbase = rowt * 128, colbase = colt * 128;
  const int wr = (wave >> 1) * 64, wc = (wave & 1) * 64;

  floatx4 acc[4][4] = {};
  const int nkt = Kdim >> 5;
  const int srow_t = tid >> 2;
  const int sslot  = tid & 3;

  for (int kt = 0; kt < nkt; ++kt) {
    const int kbase = kt << 5;
    const int chunk = kbase / 768;
    const int shift = (chunk == 0) ? s0 : ((chunk == 1) ? s1 : s2);
    const int csrc  = kbase - chunk * 768;

    __syncthreads();
    #pragma unroll
    for (int p = 0; p < 2; ++p) {
      const int row = p * 64 + srow_t;
      const int k8  = sslot ^ ((row >> 1) & 3);
      {
        const int gr = min(rowbase + row, M - 1) + shift;
        gl2lds16(A + (size_t)gr * lda + csrc + k8 * 8, lds + p * 4096 + wave * 1024);
      }
      {
        const int gn = colbase + row;
        gl2lds16(Wt + (size_t)gn * Kdim + kbase + k8 * 8, lds + 8192 + p * 4096 + wave * 1024);
      }
    }
    __syncthreads();

    const int l15 = lane & 15, kq = lane >> 4;
    short8 af[4], bfr[4];
    #pragma unroll
    for (int i = 0; i < 4; ++i) {
      const int arow = wr + i * 16 + l15;
      const int as   = kq ^ ((arow >> 1) & 3);
      af[i] = *reinterpret_cast<const short8*>(&lds[arow * 64 + as * 16]);
      const int brow = wc + i * 16 + l15;
      const int bs   = kq ^ ((brow >> 1) & 3);
      bfr[i] = *reinterpret_cast<const short8*>(&lds[8192 + brow * 64 + bs * 16]);
    }
    #pragma unroll
    for (int i = 0; i < 4; ++i)
      #pragma unroll
      for (int j = 0; j < 4; ++j)
        acc[i][j] = __builtin_amdgcn_mfma_f32_16x16x32_bf16(af[i], bfr[j], acc[i][j], 0, 0, 0);
  }

  const int l15 = lane & 15, hi = lane >> 4;
  #pragma unroll
  for (int i = 0; i < 4; ++i)
    #pragma unroll
    for (int j = 0; j < 4; ++j)
      #pragma unroll
      for (int rg = 0; rg < 4; ++rg) {
        const int r = rowbase + wr + i * 16 + hi * 4 + rg;
        const int c = colbase + wc + j * 16 + l15;
        if (r < M) {
          float v = acc[i][j][rg] + bias[c];
          if (gate_other) v = gate_other[(size_t)r * N + c] * sigmoid_f(v);
          out[(size_t)r * N + c] = v;
          if (out_bf) out_bf[(size_t)r * N + c] = __float2bfloat16(v);
        }
      }
}

__global__ void transpose_cvt(const float* __restrict__ in, bf16_t* __restrict__ out,
                              int in_ld, int out_ld)
{
  __shared__ float tile[32][33];
  const int n0 = blockIdx.x * 32, k0 = blockIdx.y * 32;
  const int tx = threadIdx.x, ty = threadIdx.y;
  #pragma unroll
  for (int yy = ty; yy < 32; yy += 8)
    tile[yy][tx] = in[(size_t)(k0 + yy) * in_ld + n0 + tx];
  __syncthreads();
  #pragma unroll
  for (int yy = ty; yy < 32; yy += 8)
    out[(size_t)(n0 + yy) * out_ld + k0 + tx] = __float2bfloat16(tile[tx][yy]);
}

__global__ void build_wct(const float* __restrict__ cw, bf16_t* __restrict__ wct) {
  const int idx = blockIdx.x * 256 + threadIdx.x;
  const int o = idx / 2304, c = idx - o * 2304;
  const int k = c / 768, i = c - k * 768;
  wct[idx] = __float2bfloat16(cw[o * 2304 + i * 3 + k]);
}

__global__ void build_bias(const float* __restrict__ bmv, const float* __restrict__ bmg,
                           const float* __restrict__ brg, const float* __restrict__ bhw,
                           float* __restrict__ out) {
  const int i = blockIdx.x * 256 + threadIdx.x;
  float v;
  if (i < 768) v = bmv[i];
  else if (i < 1536) v = bmg[i - 768];
  else if (i < 2304) v = brg[i - 1536];
  else v = bhw[i - 2304];
  out[i] = v;
}

__global__ void embed_k(const int* __restrict__ x, const float* __restrict__ emb,
                        const float* __restrict__ pos, bf16_t* __restrict__ hpad) {
  const int t = blockIdx.x, tid = threadIdx.x;
  int id = 0, tt = t - 2;
  if (t >= 2) id = x[tt];
  #pragma unroll
  for (int q = 0; q < 3; ++q) {
    const int d = tid + q * 256;
    float v = 0.f;
    if (t >= 2) v = emb[(size_t)id * DD + d] + pos[(size_t)tt * DD + d];
    hpad[(size_t)t * DD + d] = __float2bfloat16(v);
  }
}

// one block per output row t. 2 K-piece partials summed here; bias added here.
__global__ __launch_bounds__(256) void merge_ew(
    const bf16_t* __restrict__ curOldB, const float* __restrict__ curOldF,
    bf16_t* __restrict__ curNewB, float* __restrict__ curNewF,
    const float* __restrict__ t0, const float* __restrict__ t1,
    const float* __restrict__ bias_big,
    const float* __restrict__ rmsw, int step)
{
  const int t = blockIdx.x, tid = threadIdx.x;
  if (t < step) {
    const uint4* sF = (const uint4*)(curOldF + (size_t)t * DD);
    uint4* dF = (uint4*)(curNewF + (size_t)t * DD);
    if (tid < 192) dF[tid] = sF[tid];
    const uint4* sB = (const uint4*)(curOldB + (size_t)t * DD);
    uint4* dB = (uint4*)(curNewB + (size_t)t * DD);
    if (tid < 96) dB[tid] = sB[tid];
    return;
  }
  const int r = t - step;
  const size_t rb = (size_t)r * 3072;
  auto col = [&](int c) {
    return t0[rb + c] + t1[rb + c] + bias_big[c];
  };
  float mv[3]; float ss = 0.f;
  #pragma unroll
  for (int q = 0; q < 3; ++q) {
    const int d = tid + q * 256;
    const float m = col(d) * sigmoid_f(col(768 + d));
    mv[q] = m; ss += m * m;
  }
  #pragma unroll
  for (int o = 32; o >= 1; o >>= 1) ss += __shfl_down(ss, o, 64);
  __shared__ float red[4];
  if ((tid & 63) == 0) red[tid >> 6] = ss;
  __syncthreads();
  const float tot = red[0] + red[1] + red[2] + red[3];
  const float scale = rsqrtf(tot * (1.f / 768.f) + 1.1920929e-07f);
  #pragma unroll
  for (int q = 0; q < 3; ++q) {
    const int d = tid + q * 256;
    float merged = mv[q] * scale * rmsw[d];
    const float right = curOldF[(size_t)t * DD + d];
    const float left  = curOldF[(size_t)r * DD + d];
    const float hg = sigmoid_f(col(2304 + d));
    merged = hg * merged + (1.f - hg) * right;
    const float rg = sigmoid_f(col(1536 + d));
    merged = rg * merged + (1.f - rg) * (left + right) * 0.5f;
    curNewF[(size_t)t * DD + d] = merged;
    curNewB[(size_t)t * DD + d] = __float2bfloat16(merged);
  }
}

extern "C" void kernel_launch(void* const* d_in, const int* in_sizes, int n_in,
                              void* d_out, int out_size, void* d_ws, size_t ws_size,
                              hipStream_t stream) {
  const int*   x      = (const int*)  d_in[0];
  const float* emb    = (const float*)d_in[1];
  const float* pos    = (const float*)d_in[2];
  const float* conv_w = (const float*)d_in[3];
  const float* conv_b = (const float*)d_in[4];
  const float* wg1    = (const float*)d_in[5];
  const float* bg1    = (const float*)d_in[6];
  const float* wmv    = (const float*)d_in[7];
  const float* bmv    = (const float*)d_in[8];
  const float* wmg    = (const float*)d_in[9];
  const float* bmg    = (const float*)d_in[10];
  const float* wrg    = (const float*)d_in[11];
  const float* brg    = (const float*)d_in[12];
  const float* whw    = (const float*)d_in[13];
  const float* bhw    = (const float*)d_in[14];
  const float* rmsw   = (const float*)d_in[15];
  const float* wpred  = (const float*)d_in[16];
  const float* bpred  = (const float*)d_in[17];

  char* ws = (char*)d_ws;
  size_t off = 0;
  auto carve = [&](size_t bytes) { char* p = ws + off; off += (bytes + 255) & ~(size_t)255; return p; };
  bf16_t* wpred_t  = (bf16_t*)carve(32000ull * 768 * 2);
  bf16_t* Wbig_t   = (bf16_t*)carve(3072ull * 1536 * 2);
  bf16_t* wc_t     = (bf16_t*)carve(768ull * 2304 * 2);
  bf16_t* wg1_t    = (bf16_t*)carve(768ull * 768 * 2);
  float*  bias_big = (float*) carve(3072 * 4);
  bf16_t* h_pad    = (bf16_t*)carve(2050ull * 768 * 2);
  float*  hconv    = (float*) carve(2048ull * 768 * 4);
  bf16_t* hconv_bf = (bf16_t*)carve(2048ull * 768 * 2);
  bf16_t* currA_b  = (bf16_t*)carve(2048ull * 768 * 2);
  bf16_t* currB_b  = (bf16_t*)carve(2048ull * 768 * 2);
  float*  currA_f  = (float*) carve(2048ull * 768 * 4);
  float*  currB_f  = (float*) carve(2048ull * 768 * 4);
  float*  tmp      = (float*) carve(2048ull * 3072 * 4);
  // second K-piece partial buffer lives in d_out (262 MB, dead until final GEMM)
  float*  tmp2     = (float*)d_out;

  const dim3 tb(32, 8);
  hipMemsetAsync(Wbig_t + 2304ull * 1536, 0, 768ull * 1536 * 2, stream);
  transpose_cvt<<<dim3(24, 48), tb, 0, stream>>>(wmv, Wbig_t,                        768, 1536);
  transpose_cvt<<<dim3(24, 48), tb, 0, stream>>>(wmg, Wbig_t + 768ull * 1536,        768, 1536);
  transpose_cvt<<<dim3(24, 48), tb, 0, stream>>>(wrg, Wbig_t + 1536ull * 1536,       768, 1536);
  transpose_cvt<<<dim3(24, 24), tb, 0, stream>>>(whw, Wbig_t + 2304ull * 1536 + 768, 768, 1536);
  transpose_cvt<<<dim3(24, 24), tb, 0, stream>>>(wg1, wg1_t, 768, 768);
  transpose_cvt<<<dim3(1000, 24), tb, 0, stream>>>(wpred, wpred_t, 32000, 768);
  build_wct<<<6912, 256, 0, stream>>>(conv_w, wc_t);
  build_bias<<<12, 256, 0, stream>>>(bmv, bmg, brg, bhw, bias_big);

  embed_k<<<2050, 256, 0, stream>>>(x, emb, pos, h_pad);

  // causal conv as shifted GEMM (3 chunks of h_pad rows t+0,t+1,t+2)
  gemm_shift<<<96, 256, 0, stream>>>(h_pad, 768, 2048, 16, 0, 1, 2,
                                     wc_t, 2304, conv_b, hconv, 768, hconv_bf, nullptr);
  // curr0 = hconv * sigmoid(hconv @ wg1 + bg1)
  gemm_shift<<<96, 256, 0, stream>>>(hconv_bf, 768, 2048, 16, 0, 0, 0,
                                     wg1_t, 768, bg1, currA_f, 768, currA_b, hconv);

  bf16_t* curB = currA_b; float* curF = currA_f;
  bf16_t* nxtB = currB_b; float* nxtF = currB_f;
  for (int step = 1; step < 2048; step <<= 1) {
    const int M = 2048 - step;
    const int nRowT = (M + 255) / 256;
    // 2-way K-split (Kpiece=768): piece 0 = left (shift 0), piece 1 = right (shift step)
    gemm256<<<2 * nRowT * 12, 512, 0, stream>>>(
        curB, 768, M, Wbig_t, 1536, 768, nRowT, 12, 2,
        step, nullptr, tmp, tmp2, nullptr, nullptr, 3072);
    merge_ew<<<2048, 256, 0, stream>>>(curB, curF, nxtB, nxtF,
                                       tmp, tmp2, bias_big, rmsw, step);
    { bf16_t* tb_ = curB; curB = nxtB; nxtB = tb_; }
    { float*  tf_ = curF; curF = nxtF; nxtF = tf_; }
  }

  // logits = curr @ wpred + bpred
  gemm256<<<8 * 125, 512, 0, stream>>>(curB, 768, 2048, wpred_t, 768, 768, 8, 125, 1,
                                       0, bpred, (float*)d_out, nullptr, nullptr, nullptr, 32000);
}

// Round 9
// 820.041 us; speedup vs baseline: 1.3184x; 1.0561x over previous
//
#include <hip/hip_runtime.h>
#include <hip/hip_bf16.h>

typedef __attribute__((ext_vector_type(8))) short short8;
typedef __attribute__((ext_vector_type(4))) float floatx4;
typedef __hip_bfloat16 bf16_t;

#define DD 768

__device__ __forceinline__ float sigmoid_f(float x) { return 1.f / (1.f + __expf(-x)); }

__device__ __forceinline__ void gl2lds16(const void* g, void* l) {
  __builtin_amdgcn_global_load_lds((const __attribute__((address_space(1))) void*)g,
                                   (__attribute__((address_space(3))) void*)l, 16, 0, 0);
}

// ---------------------------------------------------------------------------
// 128x128-tile, BK=64, 256-thread (4 waves = 2M x 2N, 64x64/wave) bf16 GEMM.
// 64 KB LDS double-buffer -> 2 blocks/CU: cross-block overlap hides stalls
// (R8 lesson: 1-block/CU lockstep was the 25%-MfmaUtil ceiling, not prefetch
// depth). Per-768-chunk row shifts s0,s1,s2 (conv im2col / merge left|right).
// Sync per K-tile (deterministic, single wait):
//   stage(T(t+1)) into buf^1 (8 loads)  [skip on last tile]
//   s_waitcnt vmcnt(8)  [last: vmcnt(0)] -> T(t) landed, T(t+1) in flight
//   barrier; ds_read 16 b128; MFMA 32; lgkmcnt(0); barrier
// Trailing lgkmcnt(0) guarantees reads retired before buf is restaged next
// iter (guards against MFMA+wait sinking past the barrier, rule #18).
// Epilogue: +bias; optional gate fusion (out = other * sigmoid(acc+bias));
// optional bf16 mirror.
// ---------------------------------------------------------------------------
__global__ __launch_bounds__(256, 2) void gemm128(
    const bf16_t* __restrict__ A, int lda, int M, int nRowT,
    int s0, int s1, int s2,
    const bf16_t* __restrict__ Wt, int Kdim,
    const float* __restrict__ bias,
    float* __restrict__ out, int N,
    bf16_t* __restrict__ out_bf,
    const float* __restrict__ gate_other)
{
  __shared__ __attribute__((aligned(16))) unsigned char lds[65536];
  // A: [buf][128][64] bf16 at buf*16384 ; B: same at 32768 + buf*16384
  const int tid = threadIdx.x;
  const int wave = tid >> 6, lane = tid & 63;
  const int l15 = lane & 15, kq = lane >> 4;
  const int wm = wave >> 1, wn = wave & 1;

  // bijective XCD swizzle (m204), column-panel-major decode
  const int nwg = gridDim.x;
  const int q8 = nwg >> 3, r8 = nwg & 7;
  const int xcd = blockIdx.x & 7, lin = blockIdx.x >> 3;
  const int wgid = (xcd < r8 ? xcd * (q8 + 1) : r8 * (q8 + 1) + (xcd - r8) * q8) + lin;
  const int rowt = wgid % nRowT, colt = wgid / nRowT;
  const int rowbase = rowt * 128, colbase = colt * 128;

  floatx4 acc[4][4] = {};
  const int nkt = Kdim >> 6;

  auto stage = [&](int kt, int buf) {
    const int kbase = kt << 6;
    const int chunk = kbase / 768;
    const int shift = (chunk == 0) ? s0 : ((chunk == 1) ? s1 : s2);
    const int csrc  = kbase - chunk * 768;
    #pragma unroll
    for (int q = 0; q < 4; ++q) {
      const int Lb  = q * 32 + wave * 8;               // wave-uniform row base
      const int row = Lb + (lane >> 3);
      const int slotp = (lane & 7) ^ (row & 7);        // pre-swizzled source
      const int gr = min(rowbase + row, M - 1) + shift;
      gl2lds16(A + (size_t)gr * lda + csrc + slotp * 8,
               lds + buf * 16384 + Lb * 128);
      const int gn = colbase + row;                    // N multiple of 128
      gl2lds16(Wt + (size_t)gn * Kdim + kbase + slotp * 8,
               lds + 32768 + buf * 16384 + Lb * 128);
    }
  };

  stage(0, 0);
  int cur = 0;
  for (int t = 0; t < nkt; ++t) {
    if (t + 1 < nkt) {
      stage(t + 1, cur ^ 1);
      asm volatile("s_waitcnt vmcnt(8)" ::: "memory");   // T(t) landed
    } else {
      asm volatile("s_waitcnt vmcnt(0)" ::: "memory");   // queue stops: drain
    }
    __builtin_amdgcn_s_barrier();

    const unsigned char* Ab = lds + cur * 16384;
    const unsigned char* Bb = lds + 32768 + cur * 16384;
    short8 av[4][2], bv[4][2];
    #pragma unroll
    for (int i = 0; i < 4; ++i) {
      const int r = wm * 64 + i * 16 + l15;
      #pragma unroll
      for (int s = 0; s < 2; ++s) {
        const int sl = (s * 4 + kq) ^ (r & 7);
        av[i][s] = *reinterpret_cast<const short8*>(Ab + r * 128 + sl * 16);
      }
    }
    #pragma unroll
    for (int j = 0; j < 4; ++j) {
      const int r = wn * 64 + j * 16 + l15;
      #pragma unroll
      for (int s = 0; s < 2; ++s) {
        const int sl = (s * 4 + kq) ^ (r & 7);
        bv[j][s] = *reinterpret_cast<const short8*>(Bb + r * 128 + sl * 16);
      }
    }
    __builtin_amdgcn_s_setprio(1);
    #pragma unroll
    for (int i = 0; i < 4; ++i)
      #pragma unroll
      for (int j = 0; j < 4; ++j)
        #pragma unroll
        for (int s = 0; s < 2; ++s)
          acc[i][j] = __builtin_amdgcn_mfma_f32_16x16x32_bf16(
              av[i][s], bv[j][s], acc[i][j], 0, 0, 0);
    __builtin_amdgcn_s_setprio(0);
    asm volatile("s_waitcnt lgkmcnt(0)" ::: "memory");   // reads retired
    __builtin_amdgcn_s_barrier();                        // before restage
    cur ^= 1;
  }

  // epilogue: C/D layout col=lane&15, row=(lane>>4)*4+reg  [m89]
  const int hi = lane >> 4;
  #pragma unroll
  for (int i = 0; i < 4; ++i)
    #pragma unroll
    for (int j = 0; j < 4; ++j) {
      const int c = colbase + wn * 64 + j * 16 + l15;
      const float bb = bias[c];
      #pragma unroll
      for (int rg = 0; rg < 4; ++rg) {
        const int r = rowbase + wm * 64 + i * 16 + hi * 4 + rg;
        if (r < M) {
          float v = acc[i][j][rg] + bb;
          if (gate_other) v = gate_other[(size_t)r * N + c] * sigmoid_f(v);
          out[(size_t)r * N + c] = v;
          if (out_bf) out_bf[(size_t)r * N + c] = __float2bfloat16(v);
        }
      }
    }
}

__global__ void transpose_cvt(const float* __restrict__ in, bf16_t* __restrict__ out,
                              int in_ld, int out_ld)
{
  __shared__ float tile[32][33];
  const int n0 = blockIdx.x * 32, k0 = blockIdx.y * 32;
  const int tx = threadIdx.x, ty = threadIdx.y;
  #pragma unroll
  for (int yy = ty; yy < 32; yy += 8)
    tile[yy][tx] = in[(size_t)(k0 + yy) * in_ld + n0 + tx];
  __syncthreads();
  #pragma unroll
  for (int yy = ty; yy < 32; yy += 8)
    out[(size_t)(n0 + yy) * out_ld + k0 + tx] = __float2bfloat16(tile[tx][yy]);
}

__global__ void build_wct(const float* __restrict__ cw, bf16_t* __restrict__ wct) {
  const int idx = blockIdx.x * 256 + threadIdx.x;
  const int o = idx / 2304, c = idx - o * 2304;
  const int k = c / 768, i = c - k * 768;
  wct[idx] = __float2bfloat16(cw[o * 2304 + i * 3 + k]);
}

__global__ void build_bias(const float* __restrict__ bmv, const float* __restrict__ bmg,
                           const float* __restrict__ brg, const float* __restrict__ bhw,
                           float* __restrict__ out) {
  const int i = blockIdx.x * 256 + threadIdx.x;
  float v;
  if (i < 768) v = bmv[i];
  else if (i < 1536) v = bmg[i - 768];
  else if (i < 2304) v = brg[i - 1536];
  else v = bhw[i - 2304];
  out[i] = v;
}

__global__ void embed_k(const int* __restrict__ x, const float* __restrict__ emb,
                        const float* __restrict__ pos, bf16_t* __restrict__ hpad) {
  const int t = blockIdx.x, tid = threadIdx.x;
  int id = 0, tt = t - 2;
  if (t >= 2) id = x[tt];
  #pragma unroll
  for (int q = 0; q < 3; ++q) {
    const int d = tid + q * 256;
    float v = 0.f;
    if (t >= 2) v = emb[(size_t)id * DD + d] + pos[(size_t)tt * DD + d];
    hpad[(size_t)t * DD + d] = __float2bfloat16(v);
  }
}

// one block per output row t. tmp row r=t-step: [val|gate|rg|hw] (bias already
// added in GEMM epilogue — unified K, no partial sum).
__global__ __launch_bounds__(256) void merge_ew(
    const bf16_t* __restrict__ curOldB, const float* __restrict__ curOldF,
    bf16_t* __restrict__ curNewB, float* __restrict__ curNewF,
    const float* __restrict__ tmp,
    const float* __restrict__ rmsw, int step)
{
  const int t = blockIdx.x, tid = threadIdx.x;
  if (t < step) {
    const uint4* sF = (const uint4*)(curOldF + (size_t)t * DD);
    uint4* dF = (uint4*)(curNewF + (size_t)t * DD);
    if (tid < 192) dF[tid] = sF[tid];
    const uint4* sB = (const uint4*)(curOldB + (size_t)t * DD);
    uint4* dB = (uint4*)(curNewB + (size_t)t * DD);
    if (tid < 96) dB[tid] = sB[tid];
    return;
  }
  const int r = t - step;
  const float* row = tmp + (size_t)r * 3072;
  float mv[3]; float ss = 0.f;
  #pragma unroll
  for (int q = 0; q < 3; ++q) {
    const int d = tid + q * 256;
    const float m = row[d] * sigmoid_f(row[768 + d]);
    mv[q] = m; ss += m * m;
  }
  #pragma unroll
  for (int o = 32; o >= 1; o >>= 1) ss += __shfl_down(ss, o, 64);
  __shared__ float red[4];
  if ((tid & 63) == 0) red[tid >> 6] = ss;
  __syncthreads();
  const float tot = red[0] + red[1] + red[2] + red[3];
  const float scale = rsqrtf(tot * (1.f / 768.f) + 1.1920929e-07f);
  #pragma unroll
  for (int q = 0; q < 3; ++q) {
    const int d = tid + q * 256;
    float merged = mv[q] * scale * rmsw[d];
    const float right = curOldF[(size_t)t * DD + d];
    const float left  = curOldF[(size_t)r * DD + d];
    const float hg = sigmoid_f(row[2304 + d]);
    merged = hg * merged + (1.f - hg) * right;
    const float rg = sigmoid_f(row[1536 + d]);
    merged = rg * merged + (1.f - rg) * (left + right) * 0.5f;
    curNewF[(size_t)t * DD + d] = merged;
    curNewB[(size_t)t * DD + d] = __float2bfloat16(merged);
  }
}

extern "C" void kernel_launch(void* const* d_in, const int* in_sizes, int n_in,
                              void* d_out, int out_size, void* d_ws, size_t ws_size,
                              hipStream_t stream) {
  const int*   x      = (const int*)  d_in[0];
  const float* emb    = (const float*)d_in[1];
  const float* pos    = (const float*)d_in[2];
  const float* conv_w = (const float*)d_in[3];
  const float* conv_b = (const float*)d_in[4];
  const float* wg1    = (const float*)d_in[5];
  const float* bg1    = (const float*)d_in[6];
  const float* wmv    = (const float*)d_in[7];
  const float* bmv    = (const float*)d_in[8];
  const float* wmg    = (const float*)d_in[9];
  const float* bmg    = (const float*)d_in[10];
  const float* wrg    = (const float*)d_in[11];
  const float* brg    = (const float*)d_in[12];
  const float* whw    = (const float*)d_in[13];
  const float* bhw    = (const float*)d_in[14];
  const float* rmsw   = (const float*)d_in[15];
  const float* wpred  = (const float*)d_in[16];
  const float* bpred  = (const float*)d_in[17];

  char* ws = (char*)d_ws;
  size_t off = 0;
  auto carve = [&](size_t bytes) { char* p = ws + off; off += (bytes + 255) & ~(size_t)255; return p; };
  bf16_t* wpred_t  = (bf16_t*)carve(32000ull * 768 * 2);
  bf16_t* Wbig_t   = (bf16_t*)carve(3072ull * 1536 * 2);
  bf16_t* wc_t     = (bf16_t*)carve(768ull * 2304 * 2);
  bf16_t* wg1_t    = (bf16_t*)carve(768ull * 768 * 2);
  float*  bias_big = (float*) carve(3072 * 4);
  bf16_t* h_pad    = (bf16_t*)carve(2050ull * 768 * 2);
  float*  hconv    = (float*) carve(2048ull * 768 * 4);
  bf16_t* hconv_bf = (bf16_t*)carve(2048ull * 768 * 2);
  bf16_t* currA_b  = (bf16_t*)carve(2048ull * 768 * 2);
  bf16_t* currB_b  = (bf16_t*)carve(2048ull * 768 * 2);
  float*  currA_f  = (float*) carve(2048ull * 768 * 4);
  float*  currB_f  = (float*) carve(2048ull * 768 * 4);
  float*  tmp      = (float*) carve(2048ull * 3072 * 4);

  const dim3 tb(32, 8);
  hipMemsetAsync(Wbig_t + 2304ull * 1536, 0, 768ull * 1536 * 2, stream);
  transpose_cvt<<<dim3(24, 48), tb, 0, stream>>>(wmv, Wbig_t,                        768, 1536);
  transpose_cvt<<<dim3(24, 48), tb, 0, stream>>>(wmg, Wbig_t + 768ull * 1536,        768, 1536);
  transpose_cvt<<<dim3(24, 48), tb, 0, stream>>>(wrg, Wbig_t + 1536ull * 1536,       768, 1536);
  transpose_cvt<<<dim3(24, 24), tb, 0, stream>>>(whw, Wbig_t + 2304ull * 1536 + 768, 768, 1536);
  transpose_cvt<<<dim3(24, 24), tb, 0, stream>>>(wg1, wg1_t, 768, 768);
  transpose_cvt<<<dim3(1000, 24), tb, 0, stream>>>(wpred, wpred_t, 32000, 768);
  build_wct<<<6912, 256, 0, stream>>>(conv_w, wc_t);
  build_bias<<<12, 256, 0, stream>>>(bmv, bmg, brg, bhw, bias_big);

  embed_k<<<2050, 256, 0, stream>>>(x, emb, pos, h_pad);

  // causal conv as shifted GEMM (K=2304, chunk shifts 0,1,2 into h_pad)
  gemm128<<<16 * 6, 256, 0, stream>>>(h_pad, 768, 2048, 16, 0, 1, 2,
                                      wc_t, 2304, conv_b, hconv, 768, hconv_bf, nullptr);
  // curr0 = hconv * sigmoid(hconv @ wg1 + bg1)
  gemm128<<<16 * 6, 256, 0, stream>>>(hconv_bf, 768, 2048, 16, 0, 0, 0,
                                      wg1_t, 768, bg1, currA_f, 768, currA_b, hconv);

  bf16_t* curB = currA_b; float* curF = currA_f;
  bf16_t* nxtB = currB_b; float* nxtF = currB_f;
  for (int step = 1; step < 2048; step <<= 1) {
    const int M = 2048 - step;
    const int nRowT = (M + 127) / 128;
    // unified K=1536: chunk 0 = left (shift 0), chunk 1 = right (shift step)
    gemm128<<<nRowT * 24, 256, 0, stream>>>(
        curB, 768, M, nRowT, 0, step, 0, Wbig_t, 1536, bias_big, tmp, 3072,
        nullptr, nullptr);
    merge_ew<<<2048, 256, 0, stream>>>(curB, curF, nxtB, nxtF, tmp, rmsw, step);
    { bf16_t* tb_ = curB; curB = nxtB; nxtB = tb_; }
    { float*  tf_ = curF; curF = nxtF; nxtF = tf_; }
  }

  // logits = curr @ wpred + bpred
  gemm128<<<16 * 250, 256, 0, stream>>>(curB, 768, 2048, 16, 0, 0, 0,
                                        wpred_t, 768, bpred, (float*)d_out, 32000,
                                        nullptr, nullptr);
}

// Round 11
// 739.441 us; speedup vs baseline: 1.4621x; 1.1090x over previous
//
#include <hip/hip_runtime.h>
#include <hip/hip_bf16.h>

typedef __attribute__((ext_vector_type(8))) short short8;
typedef __attribute__((ext_vector_type(4))) float floatx4;
typedef __hip_bfloat16 bf16_t;

#define DD 768

__device__ __forceinline__ float sigmoid_f(float x) { return 1.f / (1.f + __expf(-x)); }

__device__ __forceinline__ void gl2lds16(const void* g, void* l) {
  __builtin_amdgcn_global_load_lds((const __attribute__((address_space(1))) void*)g,
                                   (__attribute__((address_space(3))) void*)l, 16, 0, 0);
}

// ---------------------------------------------------------------------------
// 256x256-tile, BK=64, 512-thread (8 waves = 2M x 4N) bf16 GEMM — the R8
// validated pipeline (162 us, FETCH 79 MB on the final GEMM). No K-split,
// no shifts. A double-buffered (4-phase lead), B TRIPLE-buffered (6-phase
// lead >= HBM latency). LDS = 160 KiB. Per-wave FIFO ledger (R8-verified):
//   p0: wait vmcnt(6) [last tile: 2]; barrier; read av0,bv0; stage A0(t+1)
//   p1: no wait; read bv1; stage A1(t+1)
//   p2: wait vmcnt(8) [last tile: 0]; barrier; read av1; stage B0(t+2)
//   p3: register-only MFMA; stage B1(t+2)
// Prologue queue order: B0(0),B1(0),A0(0),A1(0),B0(1),B1(1).
// ---------------------------------------------------------------------------
__global__ __launch_bounds__(512, 2) void gemm256(
    const bf16_t* __restrict__ A, int lda, int M,
    const bf16_t* __restrict__ Wt, int Kdim,
    int nRowT, int nColT,
    const float* __restrict__ bias,
    float* __restrict__ out, int N)
{
  __shared__ __attribute__((aligned(16))) unsigned char lds[163840];
  const int tid = threadIdx.x;
  const int wave = tid >> 6, lane = tid & 63;
  const int l15 = lane & 15, kq = lane >> 4;
  const int wm = wave >> 2, wn = wave & 3;

  const int nwg = gridDim.x;
  const int q8 = nwg >> 3, r8 = nwg & 7;
  const int xcd = blockIdx.x & 7, lin = blockIdx.x >> 3;
  const int wgid = (xcd < r8 ? xcd * (q8 + 1) : r8 * (q8 + 1) + (xcd - r8) * q8) + lin;
  const int rowt = wgid % nRowT, colt = wgid / nRowT;
  const int rowbase = rowt * 256, colbase = colt * 256;

  floatx4 acc[8][4] = {};
  const int nkt = Kdim >> 6;

  auto stageA = [&](int mh, int kt, int buf) {
    const int kbase = kt << 6;
    #pragma unroll
    for (int rr = 0; rr < 2; ++rr) {
      const int L = rr * 64 + wave * 8;
      const int lrow_base = (L >> 6) * 128 + mh * 64 + (L & 63);
      const int lrow = lrow_base + (lane >> 3);
      const int slotp = (lane & 7) ^ (lrow & 7);
      const int gr = min(rowbase + lrow, M - 1);
      gl2lds16(A + (size_t)gr * lda + kbase + slotp * 8,
               lds + buf * 32768 + lrow_base * 128);
    }
  };
  auto stageB = [&](int nh, int kt, int buf) {
    const int kbase = kt << 6;
    #pragma unroll
    for (int rr = 0; rr < 2; ++rr) {
      const int L = rr * 64 + wave * 8;
      const int lrow_base = (L >> 5) * 64 + nh * 32 + (L & 31);
      const int lrow = lrow_base + (lane >> 3);
      const int slotp = (lane & 7) ^ (lrow & 7);
      const int gn = colbase + lrow;
      gl2lds16(Wt + (size_t)gn * Kdim + kbase + slotp * 8,
               lds + 65536 + buf * 32768 + lrow_base * 128);
    }
  };

#define READ_A(av_, mh_) \
  _Pragma("unroll") for (int i = 0; i < 4; ++i) { \
    const int r_ = wm * 128 + (mh_) * 64 + i * 16 + l15; \
    _Pragma("unroll") for (int s = 0; s < 2; ++s) { \
      const int sl_ = (s * 4 + kq) ^ (r_ & 7); \
      av_[i][s] = *reinterpret_cast<const short8*>(Ab + r_ * 128 + sl_ * 16); } }

#define READ_B(bv_, nh_) \
  _Pragma("unroll") for (int j = 0; j < 2; ++j) { \
    const int r_ = wn * 64 + (nh_) * 32 + j * 16 + l15; \
    _Pragma("unroll") for (int s = 0; s < 2; ++s) { \
      const int sl_ = (s * 4 + kq) ^ (r_ & 7); \
      bv_[j][s] = *reinterpret_cast<const short8*>(Bb + r_ * 128 + sl_ * 16); } }

#define MFMA_Q(av_, bv_, mb_, nb_) \
  __builtin_amdgcn_s_setprio(1); \
  _Pragma("unroll") for (int i = 0; i < 4; ++i) \
    _Pragma("unroll") for (int j = 0; j < 2; ++j) \
      _Pragma("unroll") for (int s = 0; s < 2; ++s) \
        acc[(mb_) + i][(nb_) + j] = __builtin_amdgcn_mfma_f32_16x16x32_bf16( \
            av_[i][s], bv_[j][s], acc[(mb_) + i][(nb_) + j], 0, 0, 0); \
  __builtin_amdgcn_s_setprio(0);

  stageB(0, 0, 0); stageB(1, 0, 0);
  stageA(0, 0, 0); stageA(1, 0, 0);
  if (nkt > 1) { stageB(0, 1, 1); stageB(1, 1, 1); }

  short8 av0[4][2], av1[4][2], bv0[2][2], bv1[2][2];
  int curA = 0, curB = 0;
  for (int t = 0; t < nkt; ++t) {
    const bool hasA = (t + 1 < nkt), hasB = (t + 2 < nkt);
    const unsigned char* Ab = lds + curA * 32768;
    const unsigned char* Bb = lds + 65536 + curB * 32768;
    int tgtB = curB + 2; if (tgtB >= 3) tgtB -= 3;

    if (hasA) { asm volatile("s_waitcnt vmcnt(6)" ::: "memory"); }
    else      { asm volatile("s_waitcnt vmcnt(2)" ::: "memory"); }
    __builtin_amdgcn_s_barrier();
    READ_A(av0, 0)
    READ_B(bv0, 0)
    if (hasA) stageA(0, t + 1, curA ^ 1);
    MFMA_Q(av0, bv0, 0, 0)

    READ_B(bv1, 1)
    if (hasA) stageA(1, t + 1, curA ^ 1);
    MFMA_Q(av0, bv1, 0, 2)

    if (hasA) { asm volatile("s_waitcnt vmcnt(8)" ::: "memory"); }
    else      { asm volatile("s_waitcnt vmcnt(0)" ::: "memory"); }
    __builtin_amdgcn_s_barrier();
    READ_A(av1, 1)
    if (hasB) stageB(0, t + 2, tgtB);
    MFMA_Q(av1, bv0, 4, 0)

    if (hasB) stageB(1, t + 2, tgtB);
    MFMA_Q(av1, bv1, 4, 2)

    curA ^= 1; curB = (curB + 1 == 3) ? 0 : curB + 1;
  }
#undef READ_A
#undef READ_B
#undef MFMA_Q

  const int hi = lane >> 4;
  #pragma unroll
  for (int i = 0; i < 8; ++i)
    #pragma unroll
    for (int j = 0; j < 4; ++j) {
      const int c = colbase + wn * 64 + j * 16 + l15;
      const float bb = bias[c];
      #pragma unroll
      for (int rg = 0; rg < 4; ++rg) {
        const int r = rowbase + wm * 128 + i * 16 + hi * 4 + rg;
        if (r < M) out[(size_t)r * N + c] = acc[i][j][rg] + bb;
      }
    }
}

// ---------------------------------------------------------------------------
// 128x128-tile, BK=64, 256-thread (4 waves, 64x64/wave) bf16 GEMM, 64 KB LDS
// double-buffer -> 2 blocks/CU (R9 win for merge/conv/gate). Per-768-chunk
// row shifts s0,s1,s2. out (fp32) and out_bf (bf16) each optional.
// ---------------------------------------------------------------------------
__global__ __launch_bounds__(256, 2) void gemm128(
    const bf16_t* __restrict__ A, int lda, int M, int nRowT,
    int s0, int s1, int s2,
    const bf16_t* __restrict__ Wt, int Kdim,
    const float* __restrict__ bias,
    float* __restrict__ out, int N,
    bf16_t* __restrict__ out_bf,
    const float* __restrict__ gate_other)
{
  __shared__ __attribute__((aligned(16))) unsigned char lds[65536];
  const int tid = threadIdx.x;
  const int wave = tid >> 6, lane = tid & 63;
  const int l15 = lane & 15, kq = lane >> 4;
  const int wm = wave >> 1, wn = wave & 1;

  const int nwg = gridDim.x;
  const int q8 = nwg >> 3, r8 = nwg & 7;
  const int xcd = blockIdx.x & 7, lin = blockIdx.x >> 3;
  const int wgid = (xcd < r8 ? xcd * (q8 + 1) : r8 * (q8 + 1) + (xcd - r8) * q8) + lin;
  const int rowt = wgid % nRowT, colt = wgid / nRowT;
  const int rowbase = rowt * 128, colbase = colt * 128;

  floatx4 acc[4][4] = {};
  const int nkt = Kdim >> 6;

  auto stage = [&](int kt, int buf) {
    const int kbase = kt << 6;
    const int chunk = kbase / 768;
    const int shift = (chunk == 0) ? s0 : ((chunk == 1) ? s1 : s2);
    const int csrc  = kbase - chunk * 768;
    #pragma unroll
    for (int q = 0; q < 4; ++q) {
      const int Lb  = q * 32 + wave * 8;
      const int row = Lb + (lane >> 3);
      const int slotp = (lane & 7) ^ (row & 7);
      const int gr = min(rowbase + row, M - 1) + shift;
      gl2lds16(A + (size_t)gr * lda + csrc + slotp * 8,
               lds + buf * 16384 + Lb * 128);
      const int gn = colbase + row;
      gl2lds16(Wt + (size_t)gn * Kdim + kbase + slotp * 8,
               lds + 32768 + buf * 16384 + Lb * 128);
    }
  };

  stage(0, 0);
  int cur = 0;
  for (int t = 0; t < nkt; ++t) {
    if (t + 1 < nkt) {
      stage(t + 1, cur ^ 1);
      asm volatile("s_waitcnt vmcnt(8)" ::: "memory");
    } else {
      asm volatile("s_waitcnt vmcnt(0)" ::: "memory");
    }
    __builtin_amdgcn_s_barrier();

    const unsigned char* Ab = lds + cur * 16384;
    const unsigned char* Bb = lds + 32768 + cur * 16384;
    short8 av[4][2], bv[4][2];
    #pragma unroll
    for (int i = 0; i < 4; ++i) {
      const int r = wm * 64 + i * 16 + l15;
      #pragma unroll
      for (int s = 0; s < 2; ++s) {
        const int sl = (s * 4 + kq) ^ (r & 7);
        av[i][s] = *reinterpret_cast<const short8*>(Ab + r * 128 + sl * 16);
      }
    }
    #pragma unroll
    for (int j = 0; j < 4; ++j) {
      const int r = wn * 64 + j * 16 + l15;
      #pragma unroll
      for (int s = 0; s < 2; ++s) {
        const int sl = (s * 4 + kq) ^ (r & 7);
        bv[j][s] = *reinterpret_cast<const short8*>(Bb + r * 128 + sl * 16);
      }
    }
    __builtin_amdgcn_s_setprio(1);
    #pragma unroll
    for (int i = 0; i < 4; ++i)
      #pragma unroll
      for (int j = 0; j < 4; ++j)
        #pragma unroll
        for (int s = 0; s < 2; ++s)
          acc[i][j] = __builtin_amdgcn_mfma_f32_16x16x32_bf16(
              av[i][s], bv[j][s], acc[i][j], 0, 0, 0);
    __builtin_amdgcn_s_setprio(0);
    asm volatile("s_waitcnt lgkmcnt(0)" ::: "memory");
    __builtin_amdgcn_s_barrier();
    cur ^= 1;
  }

  const int hi = lane >> 4;
  #pragma unroll
  for (int i = 0; i < 4; ++i)
    #pragma unroll
    for (int j = 0; j < 4; ++j) {
      const int c = colbase + wn * 64 + j * 16 + l15;
      const float bb = bias[c];
      #pragma unroll
      for (int rg = 0; rg < 4; ++rg) {
        const int r = rowbase + wm * 64 + i * 16 + hi * 4 + rg;
        if (r < M) {
          float v = acc[i][j][rg] + bb;
          if (gate_other) v = gate_other[(size_t)r * N + c] * sigmoid_f(v);
          if (out)    out[(size_t)r * N + c] = v;
          if (out_bf) out_bf[(size_t)r * N + c] = __float2bfloat16(v);
        }
      }
    }
}

__global__ void transpose_cvt(const float* __restrict__ in, bf16_t* __restrict__ out,
                              int in_ld, int out_ld)
{
  __shared__ float tile[32][33];
  const int n0 = blockIdx.x * 32, k0 = blockIdx.y * 32;
  const int tx = threadIdx.x, ty = threadIdx.y;
  #pragma unroll
  for (int yy = ty; yy < 32; yy += 8)
    tile[yy][tx] = in[(size_t)(k0 + yy) * in_ld + n0 + tx];
  __syncthreads();
  #pragma unroll
  for (int yy = ty; yy < 32; yy += 8)
    out[(size_t)(n0 + yy) * out_ld + k0 + tx] = __float2bfloat16(tile[tx][yy]);
}

__global__ void build_wct(const float* __restrict__ cw, bf16_t* __restrict__ wct) {
  const int idx = blockIdx.x * 256 + threadIdx.x;
  const int o = idx / 2304, c = idx - o * 2304;
  const int k = c / 768, i = c - k * 768;
  wct[idx] = __float2bfloat16(cw[o * 2304 + i * 3 + k]);
}

__global__ void build_bias(const float* __restrict__ bmv, const float* __restrict__ bmg,
                           const float* __restrict__ brg, const float* __restrict__ bhw,
                           float* __restrict__ out) {
  const int i = blockIdx.x * 256 + threadIdx.x;
  float v;
  if (i < 768) v = bmv[i];
  else if (i < 1536) v = bmg[i - 768];
  else if (i < 2304) v = brg[i - 1536];
  else v = bhw[i - 2304];
  out[i] = v;
}

__global__ void embed_k(const int* __restrict__ x, const float* __restrict__ emb,
                        const float* __restrict__ pos, bf16_t* __restrict__ hpad) {
  const int t = blockIdx.x, tid = threadIdx.x;
  int id = 0, tt = t - 2;
  if (t >= 2) id = x[tt];
  #pragma unroll
  for (int q = 0; q < 3; ++q) {
    const int d = tid + q * 256;
    float v = 0.f;
    if (t >= 2) v = emb[(size_t)id * DD + d] + pos[(size_t)tt * DD + d];
    hpad[(size_t)t * DD + d] = __float2bfloat16(v);
  }
}

// one block per output row t. tmp is bf16 [2048][3072]: [val|gate|rg|hw],
// bias already added in GEMM epilogue.
__global__ __launch_bounds__(256) void merge_ew(
    const bf16_t* __restrict__ curOldB, const float* __restrict__ curOldF,
    bf16_t* __restrict__ curNewB, float* __restrict__ curNewF,
    const bf16_t* __restrict__ tmp,
    const float* __restrict__ rmsw, int step)
{
  const int t = blockIdx.x, tid = threadIdx.x;
  if (t < step) {
    const uint4* sF = (const uint4*)(curOldF + (size_t)t * DD);
    uint4* dF = (uint4*)(curNewF + (size_t)t * DD);
    if (tid < 192) dF[tid] = sF[tid];
    const uint4* sB = (const uint4*)(curOldB + (size_t)t * DD);
    uint4* dB = (uint4*)(curNewB + (size_t)t * DD);
    if (tid < 96) dB[tid] = sB[tid];
    return;
  }
  const int r = t - step;
  const bf16_t* row = tmp + (size_t)r * 3072;
  float mv[3]; float ss = 0.f;
  #pragma unroll
  for (int q = 0; q < 3; ++q) {
    const int d = tid + q * 256;
    const float m = __bfloat162float(row[d]) * sigmoid_f(__bfloat162float(row[768 + d]));
    mv[q] = m; ss += m * m;
  }
  #pragma unroll
  for (int o = 32; o >= 1; o >>= 1) ss += __shfl_down(ss, o, 64);
  __shared__ float red[4];
  if ((tid & 63) == 0) red[tid >> 6] = ss;
  __syncthreads();
  const float tot = red[0] + red[1] + red[2] + red[3];
  const float scale = rsqrtf(tot * (1.f / 768.f) + 1.1920929e-07f);
  #pragma unroll
  for (int q = 0; q < 3; ++q) {
    const int d = tid + q * 256;
    float merged = mv[q] * scale * rmsw[d];
    const float right = curOldF[(size_t)t * DD + d];
    const float left  = curOldF[(size_t)r * DD + d];
    const float hg = sigmoid_f(__bfloat162float(row[2304 + d]));
    merged = hg * merged + (1.f - hg) * right;
    const float rg = sigmoid_f(__bfloat162float(row[1536 + d]));
    merged = rg * merged + (1.f - rg) * (left + right) * 0.5f;
    curNewF[(size_t)t * DD + d] = merged;
    curNewB[(size_t)t * DD + d] = __float2bfloat16(merged);
  }
}

extern "C" void kernel_launch(void* const* d_in, const int* in_sizes, int n_in,
                              void* d_out, int out_size, void* d_ws, size_t ws_size,
                              hipStream_t stream) {
  const int*   x      = (const int*)  d_in[0];
  const float* emb    = (const float*)d_in[1];
  const float* pos    = (const float*)d_in[2];
  const float* conv_w = (const float*)d_in[3];
  const float* conv_b = (const float*)d_in[4];
  const float* wg1    = (const float*)d_in[5];
  const float* bg1    = (const float*)d_in[6];
  const float* wmv    = (const float*)d_in[7];
  const float* bmv    = (const float*)d_in[8];
  const float* wmg    = (const float*)d_in[9];
  const float* bmg    = (const float*)d_in[10];
  const float* wrg    = (const float*)d_in[11];
  const float* brg    = (const float*)d_in[12];
  const float* whw    = (const float*)d_in[13];
  const float* bhw    = (const float*)d_in[14];
  const float* rmsw   = (const float*)d_in[15];
  const float* wpred  = (const float*)d_in[16];
  const float* bpred  = (const float*)d_in[17];

  char* ws = (char*)d_ws;
  size_t off = 0;
  auto carve = [&](size_t bytes) { char* p = ws + off; off += (bytes + 255) & ~(size_t)255; return p; };
  bf16_t* wpred_t  = (bf16_t*)carve(32000ull * 768 * 2);
  bf16_t* Wbig_t   = (bf16_t*)carve(3072ull * 1536 * 2);
  bf16_t* wc_t     = (bf16_t*)carve(768ull * 2304 * 2);
  bf16_t* wg1_t    = (bf16_t*)carve(768ull * 768 * 2);
  float*  bias_big = (float*) carve(3072 * 4);
  bf16_t* h_pad    = (bf16_t*)carve(2050ull * 768 * 2);
  float*  hconv    = (float*) carve(2048ull * 768 * 4);
  bf16_t* hconv_bf = (bf16_t*)carve(2048ull * 768 * 2);
  bf16_t* currA_b  = (bf16_t*)carve(2048ull * 768 * 2);
  bf16_t* currB_b  = (bf16_t*)carve(2048ull * 768 * 2);
  float*  currA_f  = (float*) carve(2048ull * 768 * 4);
  float*  currB_f  = (float*) carve(2048ull * 768 * 4);
  bf16_t* tmp_bf   = (bf16_t*)carve(2048ull * 3072 * 2);

  const dim3 tb(32, 8);
  hipMemsetAsync(Wbig_t + 2304ull * 1536, 0, 768ull * 1536 * 2, stream);
  transpose_cvt<<<dim3(24, 48), tb, 0, stream>>>(wmv, Wbig_t,                        768, 1536);
  transpose_cvt<<<dim3(24, 48), tb, 0, stream>>>(wmg, Wbig_t + 768ull * 1536,        768, 1536);
  transpose_cvt<<<dim3(24, 48), tb, 0, stream>>>(wrg, Wbig_t + 1536ull * 1536,       768, 1536);
  transpose_cvt<<<dim3(24, 24), tb, 0, stream>>>(whw, Wbig_t + 2304ull * 1536 + 768, 768, 1536);
  transpose_cvt<<<dim3(24, 24), tb, 0, stream>>>(wg1, wg1_t, 768, 768);
  transpose_cvt<<<dim3(1000, 24), tb, 0, stream>>>(wpred, wpred_t, 32000, 768);
  build_wct<<<6912, 256, 0, stream>>>(conv_w, wc_t);
  build_bias<<<12, 256, 0, stream>>>(bmv, bmg, brg, bhw, bias_big);

  embed_k<<<2050, 256, 0, stream>>>(x, emb, pos, h_pad);

  // causal conv as shifted GEMM (K=2304, chunk shifts 0,1,2 into h_pad)
  gemm128<<<16 * 6, 256, 0, stream>>>(h_pad, 768, 2048, 16, 0, 1, 2,
                                      wc_t, 2304, conv_b, hconv, 768, hconv_bf, nullptr);
  // curr0 = hconv * sigmoid(hconv @ wg1 + bg1)
  gemm128<<<16 * 6, 256, 0, stream>>>(hconv_bf, 768, 2048, 16, 0, 0, 0,
                                      wg1_t, 768, bg1, currA_f, 768, currA_b, hconv);

  bf16_t* curB = currA_b; float* curF = currA_f;
  bf16_t* nxtB = currB_b; float* nxtF = currB_f;
  for (int step = 1; step < 2048; step <<= 1) {
    const int M = 2048 - step;
    const int nRowT = (M + 127) / 128;
    // unified K=1536: chunk 0 = left (shift 0), chunk 1 = right (shift step);
    // bf16-only output (tmp_bf) halves partial traffic
    gemm128<<<nRowT * 24, 256, 0, stream>>>(
        curB, 768, M, nRowT, 0, step, 0, Wbig_t, 1536, bias_big,
        nullptr, 3072, tmp_bf, nullptr);
    merge_ew<<<2048, 256, 0, stream>>>(curB, curF, nxtB, nxtF, tmp_bf, rmsw, step);
    { bf16_t* tb_ = curB; curB = nxtB; nxtB = tb_; }
    { float*  tf_ = curF; curF = nxtF; nxtF = tf_; }
  }

  // logits = curr @ wpred + bpred  (R8-validated 256^2 pipeline)
  gemm256<<<8 * 125, 512, 0, stream>>>(curB, 768, 2048, wpred_t, 768, 8, 125,
                                       bpred, (float*)d_out, 32000);
}